// Round 2
// baseline (2843.053 us; speedup 1.0000x reference)
//
#include <hip/hip_runtime.h>
#include <stdint.h>

#define NQ 8192
#define NK 20000
#define RD 512
#define NT 157      // ceil(20000/128)
#define TSPLIT 79   // tiles in split 0 (split 1 gets 78)

typedef float f32x4 __attribute__((ext_vector_type(4)));
typedef short s16x8 __attribute__((ext_vector_type(8)));

__device__ __forceinline__ unsigned short bf16_rn(float x) {
    uint32_t u = __float_as_uint(x);
    return (unsigned short)((u + 0x7FFFu + ((u >> 16) & 1)) >> 16);
}

// ---------------- preconv: M(fp32) -> Mhi (RTZ hi), Mlo (RN residual), MT (RN bf16, transposed) ----
__global__ void preconv_kernel(const float* __restrict__ M,
                               unsigned short* __restrict__ Mhi,
                               unsigned short* __restrict__ Mlo,
                               unsigned short* __restrict__ MT) {
    __shared__ float tilef[64 * 65];
    const int k0 = blockIdx.x * 64, r0 = blockIdx.y * 64;
    const int t = threadIdx.x;
#pragma unroll
    for (int i = 0; i < 16; i++) {
        int e = t + i * 256;
        int kr = e >> 6, cc = e & 63;
        int key = k0 + kr;
        if (key < NK) {
            float x = M[(size_t)key * RD + r0 + cc];
            uint32_t u = __float_as_uint(x);
            Mhi[(size_t)key * RD + r0 + cc] = (unsigned short)(u >> 16);
            Mlo[(size_t)key * RD + r0 + cc] = bf16_rn(x - __uint_as_float(u & 0xFFFF0000u));
            tilef[cc * 65 + kr] = x;
        }
    }
    __syncthreads();
#pragma unroll
    for (int i = 0; i < 16; i++) {
        int e = t + i * 256;
        int rr = e >> 6, kk = e & 63;
        int key = k0 + kk;
        if (key < NK) MT[(size_t)(r0 + rr) * NK + key] = bf16_rn(tilef[rr * 65 + kk]);
    }
}

// ---------------- flash kernel v2: barrier-free K loop, register-direct loads ----------------
// 512 thr = 8 waves; wave w = col-eighth ch (1 col block of 16 keys in the 128-key tile),
// each wave covers BOTH 16-row strips. Q (hi/lo) in LDS frag-linear. K/MT loaded
// global->VGPR in exactly MFMA B-layout. 2 barriers/tile (softmax exchanges only).
__global__ __launch_bounds__(512, 4) void flash2_kernel(
        const float* __restrict__ h,
        const unsigned short* __restrict__ Mhi,
        const unsigned short* __restrict__ Mlo,
        const unsigned short* __restrict__ MT,
        float* __restrict__ out,
        float* __restrict__ Opart,
        float* __restrict__ mpart,
        float* __restrict__ lpart,
        int nsplit) {
    __shared__ unsigned short qbuf[2 * 16 * 512 * 2];  // [hi|lo], each 2 strips x 16 steps x 512 u16
    __shared__ unsigned short pbuf[8 * 64 * 8];        // 8 P A-frags (4 ksteps x 2 strips)
    __shared__ float smaxb[8 * 2 * 16];                // [ch][strip][row16]
    __shared__ float ssumb[8 * 2 * 16];

    const int tid = threadIdx.x;
    const int ch = tid >> 6, l = tid & 63;
    const int l15 = l & 15, q4 = l >> 4;

    int qb, split;
    if (nsplit == 2) { qb = blockIdx.x & 255; split = blockIdx.x >> 8; }
    else             { qb = blockIdx.x;       split = 0; }
    const int koff = (split == 0) ? 0 : TSPLIT * 128;
    const int ntl  = (nsplit == 2) ? ((split == 0) ? TSPLIT : (NT - TSPLIT)) : NT;
    const int qbase = qb * 32;

    // ---- stage Q -> LDS (hi RTZ / lo RN), frag-linear ----
#pragma unroll
    for (int i = 0; i < 4; i++) {
        int g = tid + i * 512;                  // 0..2047
        int row = g >> 6, s = (g >> 2) & 15, qg = g & 3;
        int strip = row >> 4, lrow = row & 15;
        const float* src = h + (size_t)(qbase + row) * RD + s * 32 + qg * 8;
        f32x4 a = *(const f32x4*)src;
        f32x4 b = *(const f32x4*)(src + 4);
        s16x8 hi8, lo8;
#pragma unroll
        for (int j = 0; j < 8; j++) {
            float x = (j < 4) ? a[j] : b[j - 4];
            uint32_t u = __float_as_uint(x);
            hi8[j] = (short)(u >> 16);
            lo8[j] = (short)bf16_rn(x - __uint_as_float(u & 0xFFFF0000u));
        }
        int off = ((strip * 16 + s) * 512 + (qg * 16 + lrow) * 8);
        *(s16x8*)&qbuf[off] = hi8;
        *(s16x8*)&qbuf[16384 + off] = lo8;
    }
    __syncthreads();

    f32x4 O[2][4];
#pragma unroll
    for (int st = 0; st < 2; st++)
#pragma unroll
        for (int ct = 0; ct < 4; ct++) O[st][ct] = 0.f;
    f32x4 m_run[2], l_run[2];
    m_run[0] = -3e38f; m_run[1] = -3e38f; l_run[0] = 0.f; l_run[1] = 0.f;

    // preload tile-0 kstep-0 K frags
    const unsigned short* kph0 = Mhi + (size_t)(koff + ch * 16 + l15) * RD + q4 * 8;
    const unsigned short* kpl0 = Mlo + (size_t)(koff + ch * 16 + l15) * RD + q4 * 8;
    s16x8 khNxt = *(const s16x8*)kph0;
    s16x8 klNxt = *(const s16x8*)kpl0;

    for (int tile = 0; tile < ntl; tile++) {
        const int keyg = koff + tile * 128 + ch * 16 + l15;
        const unsigned short* kph = Mhi + (size_t)keyg * RD + q4 * 8;
        const unsigned short* kpl = Mlo + (size_t)keyg * RD + q4 * 8;

        // ================= S phase (no barriers) =================
        f32x4 Ca = 0.f, Cb = 0.f;
        s16x8 khC = khNxt, klC = klNxt;
#pragma unroll
        for (int s = 0; s < 16; s++) {
            s16x8 khN = khC, klN = klC;
            if (s < 15) {
                khN = *(const s16x8*)(kph + (s + 1) * 32);
                klN = *(const s16x8*)(kpl + (s + 1) * 32);
            }
            s16x8 qh0 = *(const s16x8*)&qbuf[s * 512 + l * 8];
            s16x8 ql0 = *(const s16x8*)&qbuf[16384 + s * 512 + l * 8];
            s16x8 qh1 = *(const s16x8*)&qbuf[(16 + s) * 512 + l * 8];
            s16x8 ql1 = *(const s16x8*)&qbuf[16384 + (16 + s) * 512 + l * 8];
            Ca = __builtin_amdgcn_mfma_f32_16x16x32_bf16(qh0, khC, Ca, 0, 0, 0);
            Cb = __builtin_amdgcn_mfma_f32_16x16x32_bf16(qh1, khC, Cb, 0, 0, 0);
            Ca = __builtin_amdgcn_mfma_f32_16x16x32_bf16(ql0, khC, Ca, 0, 0, 0);
            Cb = __builtin_amdgcn_mfma_f32_16x16x32_bf16(ql1, khC, Cb, 0, 0, 0);
            Ca = __builtin_amdgcn_mfma_f32_16x16x32_bf16(qh0, klC, Ca, 0, 0, 0);
            Cb = __builtin_amdgcn_mfma_f32_16x16x32_bf16(qh1, klC, Cb, 0, 0, 0);
            khC = khN; klC = klN;
        }
        // mask tail keys
        if (tile == ntl - 1) {
            if (keyg >= NK) { Ca = -3e38f; Cb = -3e38f; }
        }

        // prefetch PV B-frags for this tile (latency hidden by softmax + barriers)
        const unsigned short* mtp = MT + (size_t)(ch * 64 + l15) * NK + koff + tile * 128 + q4 * 8;
        s16x8 btC[4];
#pragma unroll
        for (int sk = 0; sk < 4; sk++) btC[sk] = *(const s16x8*)(mtp + sk * 32);

        // ================= softmax =================
        f32x4 mx[2]; mx[0] = Ca; mx[1] = Cb;
#pragma unroll
        for (int d = 1; d < 16; d <<= 1) {
#pragma unroll
            for (int v = 0; v < 4; v++) {
                mx[0][v] = fmaxf(mx[0][v], __shfl_xor(mx[0][v], d, 16));
                mx[1][v] = fmaxf(mx[1][v], __shfl_xor(mx[1][v], d, 16));
            }
        }
        if (l15 == 0) {
            *(f32x4*)&smaxb[(ch * 2 + 0) * 16 + q4 * 4] = mx[0];
            *(f32x4*)&smaxb[(ch * 2 + 1) * 16 + q4 * 4] = mx[1];
        }
        __syncthreads();   // B1
        f32x4 mnew[2]; mnew[0] = m_run[0]; mnew[1] = m_run[1];
#pragma unroll
        for (int cc = 0; cc < 8; cc++) {
#pragma unroll
            for (int st = 0; st < 2; st++) {
                f32x4 tv = *(const f32x4*)&smaxb[(cc * 2 + st) * 16 + q4 * 4];
#pragma unroll
                for (int v = 0; v < 4; v++) mnew[st][v] = fmaxf(mnew[st][v], tv[v]);
            }
        }
        f32x4 alpha[2];
#pragma unroll
        for (int st = 0; st < 2; st++)
#pragma unroll
            for (int v = 0; v < 4; v++) {
                alpha[st][v] = __expf(m_run[st][v] - mnew[st][v]);
                m_run[st][v] = mnew[st][v];
            }
        // p + pbuf write + partial sums
        const int key_loc = ch * 16 + l15;
        const int sk0 = key_loc >> 5, kq = (key_loc >> 3) & 3, jj = key_loc & 7;
        f32x4 ps[2]; ps[0] = 0.f; ps[1] = 0.f;
#pragma unroll
        for (int st = 0; st < 2; st++) {
#pragma unroll
            for (int v = 0; v < 4; v++) {
                float sv = (st == 0) ? Ca[v] : Cb[v];
                float p = __expf(sv - mnew[st][v]);
                ps[st][v] += p;
                pbuf[((sk0 * 2 + st) * 64 + (q4 * 4 + v) + 16 * kq) * 8 + jj] = bf16_rn(p);
            }
        }
#pragma unroll
        for (int d = 1; d < 16; d <<= 1) {
#pragma unroll
            for (int v = 0; v < 4; v++) {
                ps[0][v] += __shfl_xor(ps[0][v], d, 16);
                ps[1][v] += __shfl_xor(ps[1][v], d, 16);
            }
        }
        if (l15 == 0) {
            *(f32x4*)&ssumb[(ch * 2 + 0) * 16 + q4 * 4] = ps[0];
            *(f32x4*)&ssumb[(ch * 2 + 1) * 16 + q4 * 4] = ps[1];
        }
        __syncthreads();   // B2
        f32x4 ts[2]; ts[0] = 0.f; ts[1] = 0.f;
#pragma unroll
        for (int cc = 0; cc < 8; cc++) {
            ts[0] += *(const f32x4*)&ssumb[(cc * 2 + 0) * 16 + q4 * 4];
            ts[1] += *(const f32x4*)&ssumb[(cc * 2 + 1) * 16 + q4 * 4];
        }
#pragma unroll
        for (int st = 0; st < 2; st++)
#pragma unroll
            for (int v = 0; v < 4; v++) l_run[st][v] = l_run[st][v] * alpha[st][v] + ts[st][v];
        // O rescale
#pragma unroll
        for (int st = 0; st < 2; st++)
#pragma unroll
            for (int ct = 0; ct < 4; ct++)
#pragma unroll
                for (int v = 0; v < 4; v++) O[st][ct][v] *= alpha[st][v];
        // P A-frags
        s16x8 pa[2][4];
#pragma unroll
        for (int st = 0; st < 2; st++)
#pragma unroll
            for (int sk = 0; sk < 4; sk++)
                pa[st][sk] = *(const s16x8*)&pbuf[((sk * 2 + st) * 64 + l) * 8];

        // prefetch next tile's kstep-0 K frags (lives across barrier-free PV)
        if (tile < ntl - 1) {
            const int kg2 = koff + (tile + 1) * 128 + ch * 16 + l15;
            khNxt = *(const s16x8*)(Mhi + (size_t)kg2 * RD + q4 * 8);
            klNxt = *(const s16x8*)(Mlo + (size_t)kg2 * RD + q4 * 8);
        }

        // ================= PV phase (no barriers) =================
#pragma unroll
        for (int ct = 0; ct < 4; ct++) {
            s16x8 btN[4];
            if (ct < 3) {
#pragma unroll
                for (int sk = 0; sk < 4; sk++)
                    btN[sk] = *(const s16x8*)(mtp + (size_t)(ct + 1) * 16 * NK + sk * 32);
            }
#pragma unroll
            for (int sk = 0; sk < 4; sk++) {
                O[0][ct] = __builtin_amdgcn_mfma_f32_16x16x32_bf16(pa[0][sk], btC[sk], O[0][ct], 0, 0, 0);
                O[1][ct] = __builtin_amdgcn_mfma_f32_16x16x32_bf16(pa[1][sk], btC[sk], O[1][ct], 0, 0, 0);
            }
            if (ct < 3) {
#pragma unroll
                for (int sk = 0; sk < 4; sk++) btC[sk] = btN[sk];
            }
        }
    }

    // ================= epilogue =================
    if (nsplit == 2) {
        float* Od = Opart + (size_t)split * NQ * RD;
#pragma unroll
        for (int st = 0; st < 2; st++)
#pragma unroll
            for (int ct = 0; ct < 4; ct++)
#pragma unroll
                for (int v = 0; v < 4; v++)
                    Od[(size_t)(qbase + st * 16 + q4 * 4 + v) * RD + (ch * 4 + ct) * 16 + l15] =
                        O[st][ct][v];
        if (ch == 0 && l15 == 0) {
#pragma unroll
            for (int st = 0; st < 2; st++)
#pragma unroll
                for (int v = 0; v < 4; v++) {
                    mpart[split * NQ + qbase + st * 16 + q4 * 4 + v] = m_run[st][v];
                    lpart[split * NQ + qbase + st * 16 + q4 * 4 + v] = l_run[st][v];
                }
        }
    } else {
#pragma unroll
        for (int st = 0; st < 2; st++)
#pragma unroll
            for (int ct = 0; ct < 4; ct++)
#pragma unroll
                for (int v = 0; v < 4; v++)
                    out[(size_t)(qbase + st * 16 + q4 * 4 + v) * RD + (ch * 4 + ct) * 16 + l15] =
                        O[st][ct][v] / l_run[st][v];
    }
}

// ---------------- combine split-K partials ----------------
__global__ __launch_bounds__(256) void combine_kernel(const float* __restrict__ Opart,
                                                      const float* __restrict__ mpart,
                                                      const float* __restrict__ lpart,
                                                      float* __restrict__ out) {
    const int t = threadIdx.x;
    const int row = blockIdx.x * 2 + (t >> 7);
    const int d = (t & 127) * 4;
    float m0 = mpart[row], m1 = mpart[NQ + row];
    float l0 = lpart[row], l1 = lpart[NQ + row];
    float m = fmaxf(m0, m1);
    float w0 = __expf(m0 - m), w1 = __expf(m1 - m);
    float inv = 1.f / (w0 * l0 + w1 * l1);
    f32x4 o0 = *(const f32x4*)&Opart[(size_t)row * RD + d];
    f32x4 o1 = *(const f32x4*)&Opart[(size_t)NQ * RD + (size_t)row * RD + d];
    f32x4 r;
#pragma unroll
    for (int v = 0; v < 4; v++) r[v] = (o0[v] * w0 + o1[v] * w1) * inv;
    *(f32x4*)&out[(size_t)row * RD + d] = r;
}

// ---------------- fallback (ws too small): fp32, slow but exact ----------------
__global__ __launch_bounds__(256) void naive_kernel(const float* __restrict__ h,
                                                    const float* __restrict__ M,
                                                    float* __restrict__ out) {
    __shared__ float hs[16 * 520];
    __shared__ float ms[8 * 520];
    __shared__ float sdot[2][128];
    __shared__ float sm[16], sl[16], sal[16], sp[16][8];
    const int t = threadIdx.x;
    const int qbase = blockIdx.x * 16;
#pragma unroll
    for (int i = 0; i < 32; i++) {
        int e = t + i * 256;
        int row = e >> 9, col = e & 511;
        hs[row * 520 + col] = h[(size_t)(qbase + row) * RD + col];
    }
    if (t < 16) { sm[t] = -3e38f; sl[t] = 0.f; }
    float Oacc[32];
#pragma unroll
    for (int i = 0; i < 32; i++) Oacc[i] = 0.f;
    const int q = t >> 4;
    const int eb = (t & 15) * 32;

    for (int k0 = 0; k0 < NK; k0 += 8) {
        __syncthreads();
#pragma unroll
        for (int i = 0; i < 16; i++) {
            int e = t + i * 256;
            if (e < 4096) {
                int kk = e >> 9, col = e & 511;
                ms[kk * 520 + col] = M[(size_t)(k0 + kk) * RD + col];
            }
        }
        __syncthreads();
        {
            int pair = t & 127, half = t >> 7;
            int qq = pair & 15, kk = pair >> 4;
            const float* hp = &hs[qq * 520 + half * 256];
            const float* mp = &ms[kk * 520 + half * 256];
            float acc = 0.f;
#pragma unroll 8
            for (int e = 0; e < 256; e++) acc += hp[e] * mp[e];
            sdot[half][pair] = acc;
        }
        __syncthreads();
        if (t < 16) {
            int qq = t;
            float s8[8];
#pragma unroll
            for (int kk = 0; kk < 8; kk++) s8[kk] = sdot[0][qq + 16 * kk] + sdot[1][qq + 16 * kk];
            float mn = sm[qq];
#pragma unroll
            for (int kk = 0; kk < 8; kk++) mn = fmaxf(mn, s8[kk]);
            float al = __expf(sm[qq] - mn);
            float addl = 0.f;
#pragma unroll
            for (int kk = 0; kk < 8; kk++) { float p = __expf(s8[kk] - mn); sp[qq][kk] = p; addl += p; }
            sm[qq] = mn; sl[qq] = sl[qq] * al + addl; sal[qq] = al;
        }
        __syncthreads();
        {
            float al = sal[q];
#pragma unroll
            for (int i = 0; i < 32; i++) Oacc[i] *= al;
#pragma unroll
            for (int kk = 0; kk < 8; kk++) {
                float p = sp[q][kk];
                const float* mp = &ms[kk * 520 + eb];
#pragma unroll
                for (int i = 0; i < 32; i++) Oacc[i] += p * mp[i];
            }
        }
    }
    __syncthreads();
    float inv = 1.f / sl[q];
#pragma unroll
    for (int i = 0; i < 32; i++) out[(size_t)(qbase + q) * RD + eb + i] = Oacc[i] * inv;
}

extern "C" void kernel_launch(void* const* d_in, const int* in_sizes, int n_in,
                              void* d_out, int out_size, void* d_ws, size_t ws_size,
                              hipStream_t stream) {
    const float* h = (const float*)d_in[0];
    const float* M = (const float*)d_in[1];
    float* out = (float*)d_out;
    const size_t seg = (size_t)NK * RD;                         // u16 elems per converted buffer
    const size_t base_bytes = (seg * 3ull + 8192ull) * 2ull;    // Mhi+Mlo+MT + tail pad
    const size_t opart_bytes = 2ull * NQ * RD * 4ull;
    const size_t stat_bytes = 2ull * 2ull * NQ * 4ull;
    const size_t need_split = base_bytes + opart_bytes + stat_bytes;
    const size_t need_basic = base_bytes;

    if (ws_size >= need_basic) {
        unsigned short* Mhi = (unsigned short*)d_ws;
        unsigned short* Mlo = Mhi + seg;
        unsigned short* MT  = Mlo + seg;
        float* Opart = (float*)((char*)d_ws + base_bytes);
        float* mpart = Opart + 2ull * NQ * RD;
        float* lpart = mpart + 2ull * NQ;
        preconv_kernel<<<dim3(313, 8), 256, 0, stream>>>(M, Mhi, Mlo, MT);
        if (ws_size >= need_split) {
            flash2_kernel<<<512, 512, 0, stream>>>(h, Mhi, Mlo, MT, out, Opart, mpart, lpart, 2);
            combine_kernel<<<NQ / 2, 256, 0, stream>>>(Opart, mpart, lpart, out);
        } else {
            flash2_kernel<<<256, 512, 0, stream>>>(h, Mhi, Mlo, MT, out, Opart, mpart, lpart, 1);
        }
    } else {
        naive_kernel<<<512, 256, 0, stream>>>(h, M, out);
    }
}

// Round 3
// 1858.117 us; speedup vs baseline: 1.5301x; 1.5301x over previous
//
#include <hip/hip_runtime.h>
#include <stdint.h>

#define NQ 8192
#define NK 20000
#define RD 512
#define NT 157      // ceil(20000/128)

typedef float f32x4 __attribute__((ext_vector_type(4)));
typedef short s16x8 __attribute__((ext_vector_type(8)));

__device__ __forceinline__ unsigned short bf16_rn(float x) {
    uint32_t u = __float_as_uint(x);
    return (unsigned short)((u + 0x7FFFu + ((u >> 16) & 1)) >> 16);
}

// ---------------- preconv: M(fp32) -> Mhi (RTZ hi), Mlo (RN residual), MT (RN bf16, transposed) ----
__global__ void preconv_kernel(const float* __restrict__ M,
                               unsigned short* __restrict__ Mhi,
                               unsigned short* __restrict__ Mlo,
                               unsigned short* __restrict__ MT) {
    __shared__ float tilef[64 * 65];
    const int k0 = blockIdx.x * 64, r0 = blockIdx.y * 64;
    const int t = threadIdx.x;
#pragma unroll
    for (int i = 0; i < 16; i++) {
        int e = t + i * 256;
        int kr = e >> 6, cc = e & 63;
        int key = k0 + kr;
        if (key < NK) {
            float x = M[(size_t)key * RD + r0 + cc];
            uint32_t u = __float_as_uint(x);
            Mhi[(size_t)key * RD + r0 + cc] = (unsigned short)(u >> 16);
            Mlo[(size_t)key * RD + r0 + cc] = bf16_rn(x - __uint_as_float(u & 0xFFFF0000u));
            tilef[cc * 65 + kr] = x;
        }
    }
    __syncthreads();
#pragma unroll
    for (int i = 0; i < 16; i++) {
        int e = t + i * 256;
        int rr = e >> 6, kk = e & 63;
        int key = k0 + kk;
        if (key < NK) MT[(size_t)(r0 + rr) * NK + key] = bf16_rn(tilef[rr * 65 + kk]);
    }
}

// ---------------- flash kernel v3 ----------------
// grid 256 x 512 thr (8 waves). Block: 32 query rows; tile: 128 keys.
// wave = col-eighth ch (16 keys), both 16-row strips. Q (hi/lo) in LDS frag-linear.
// K loaded global->VGPR in MFMA B-layout, SW-pipelined depth 2. 2 barriers/tile.
// launch_bounds(512,2): 256-VGPR budget -> NO spills (round-2 failure mode).
// grid 256 = 1 block/CU; all blocks sweep tiles in same order -> L2 convoy reuse.
__global__ __launch_bounds__(512, 2) void flash3_kernel(
        const float* __restrict__ h,
        const unsigned short* __restrict__ Mhi,
        const unsigned short* __restrict__ Mlo,
        const unsigned short* __restrict__ MT,
        float* __restrict__ out) {
    __shared__ unsigned short qbuf[2 * 16 * 512 * 2];  // [hi|lo], 2 strips x 16 steps x 512 u16
    __shared__ unsigned short pbuf[8 * 64 * 8];        // 8 P A-frags (4 ksteps x 2 strips)
    __shared__ float smaxb[8 * 2 * 16];                // [ch][strip][row16]
    __shared__ float ssumb[8 * 2 * 16];

    const int tid = threadIdx.x;
    const int ch = tid >> 6, l = tid & 63;
    const int l15 = l & 15, q4 = l >> 4;
    const int qbase = blockIdx.x * 32;

    // ---- stage Q -> LDS (hi RTZ / lo RN), frag-linear ----
#pragma unroll
    for (int i = 0; i < 4; i++) {
        int g = tid + i * 512;                  // 0..2047  = row*64 + s*4 + qg
        int row = g >> 6, s = (g >> 2) & 15, qg = g & 3;
        int strip = row >> 4, lrow = row & 15;
        const float* src = h + (size_t)(qbase + row) * RD + s * 32 + qg * 8;
        f32x4 a = *(const f32x4*)src;
        f32x4 b = *(const f32x4*)(src + 4);
        s16x8 hi8, lo8;
#pragma unroll
        for (int j = 0; j < 8; j++) {
            float x = (j < 4) ? a[j] : b[j - 4];
            uint32_t u = __float_as_uint(x);
            hi8[j] = (short)(u >> 16);
            lo8[j] = (short)bf16_rn(x - __uint_as_float(u & 0xFFFF0000u));
        }
        int off = ((strip * 16 + s) * 512 + (qg * 16 + lrow) * 8);
        *(s16x8*)&qbuf[off] = hi8;
        *(s16x8*)&qbuf[16384 + off] = lo8;
    }
    __syncthreads();

    f32x4 O[2][4];
#pragma unroll
    for (int st = 0; st < 2; st++)
#pragma unroll
        for (int ct = 0; ct < 4; ct++) O[st][ct] = 0.f;
    f32x4 m_run[2], l_run[2];
    m_run[0] = -3e38f; m_run[1] = -3e38f; l_run[0] = 0.f; l_run[1] = 0.f;

    // SW pipeline regs: kstep s and s+1 in flight
    s16x8 khq[2], klq[2];
    {
        const size_t b0 = (size_t)(ch * 16 + l15) * RD + q4 * 8;
        khq[0] = *(const s16x8*)(Mhi + b0);
        klq[0] = *(const s16x8*)(Mlo + b0);
        khq[1] = *(const s16x8*)(Mhi + b0 + 32);
        klq[1] = *(const s16x8*)(Mlo + b0 + 32);
    }

    for (int tile = 0; tile < NT; tile++) {
        const int keyg = tile * 128 + ch * 16 + l15;
        const unsigned short* kph = Mhi + (size_t)keyg * RD + q4 * 8;
        const unsigned short* kpl = Mlo + (size_t)keyg * RD + q4 * 8;

        // ================= S phase (no barriers, depth-2 pipeline) =================
        f32x4 Ca = 0.f, Cb = 0.f;
#pragma unroll
        for (int s = 0; s < 16; s++) {
            s16x8 kh = khq[s & 1], kl = klq[s & 1];
            if (s < 14) {
                khq[s & 1] = *(const s16x8*)(kph + (s + 2) * 32);
                klq[s & 1] = *(const s16x8*)(kpl + (s + 2) * 32);
            }
            s16x8 qh0 = *(const s16x8*)&qbuf[s * 512 + l * 8];
            s16x8 ql0 = *(const s16x8*)&qbuf[16384 + s * 512 + l * 8];
            s16x8 qh1 = *(const s16x8*)&qbuf[(16 + s) * 512 + l * 8];
            s16x8 ql1 = *(const s16x8*)&qbuf[16384 + (16 + s) * 512 + l * 8];
            Ca = __builtin_amdgcn_mfma_f32_16x16x32_bf16(qh0, kh, Ca, 0, 0, 0);
            Cb = __builtin_amdgcn_mfma_f32_16x16x32_bf16(qh1, kh, Cb, 0, 0, 0);
            Ca = __builtin_amdgcn_mfma_f32_16x16x32_bf16(ql0, kh, Ca, 0, 0, 0);
            Cb = __builtin_amdgcn_mfma_f32_16x16x32_bf16(ql1, kh, Cb, 0, 0, 0);
            Ca = __builtin_amdgcn_mfma_f32_16x16x32_bf16(qh0, kl, Ca, 0, 0, 0);
            Cb = __builtin_amdgcn_mfma_f32_16x16x32_bf16(qh1, kl, Cb, 0, 0, 0);
        }
        // mask tail keys
        if (tile == NT - 1) {
            if (keyg >= NK) { Ca = -3e38f; Cb = -3e38f; }
        }

        // prefetch this tile's first PV B-frags (latency hidden by softmax)
        const unsigned short* mtp = MT + (size_t)(ch * 64 + l15) * NK + tile * 128 + q4 * 8;
        s16x8 btC[4];
#pragma unroll
        for (int sk = 0; sk < 4; sk++) btC[sk] = *(const s16x8*)(mtp + sk * 32);

        // ================= softmax =================
        f32x4 mx[2]; mx[0] = Ca; mx[1] = Cb;
#pragma unroll
        for (int d = 1; d < 16; d <<= 1) {
#pragma unroll
            for (int v = 0; v < 4; v++) {
                mx[0][v] = fmaxf(mx[0][v], __shfl_xor(mx[0][v], d, 16));
                mx[1][v] = fmaxf(mx[1][v], __shfl_xor(mx[1][v], d, 16));
            }
        }
        if (l15 == 0) {
            *(f32x4*)&smaxb[(ch * 2 + 0) * 16 + q4 * 4] = mx[0];
            *(f32x4*)&smaxb[(ch * 2 + 1) * 16 + q4 * 4] = mx[1];
        }
        __syncthreads();   // B1
        f32x4 mnew[2]; mnew[0] = m_run[0]; mnew[1] = m_run[1];
#pragma unroll
        for (int cc = 0; cc < 8; cc++) {
#pragma unroll
            for (int st = 0; st < 2; st++) {
                f32x4 tv = *(const f32x4*)&smaxb[(cc * 2 + st) * 16 + q4 * 4];
#pragma unroll
                for (int v = 0; v < 4; v++) mnew[st][v] = fmaxf(mnew[st][v], tv[v]);
            }
        }
        f32x4 alpha[2];
#pragma unroll
        for (int st = 0; st < 2; st++)
#pragma unroll
            for (int v = 0; v < 4; v++) {
                alpha[st][v] = __expf(m_run[st][v] - mnew[st][v]);
                m_run[st][v] = mnew[st][v];
            }
        // p + pbuf write + partial sums
        const int key_loc = ch * 16 + l15;
        const int sk0 = key_loc >> 5, kq = (key_loc >> 3) & 3, jj = key_loc & 7;
        f32x4 ps[2]; ps[0] = 0.f; ps[1] = 0.f;
#pragma unroll
        for (int st = 0; st < 2; st++) {
#pragma unroll
            for (int v = 0; v < 4; v++) {
                float sv = (st == 0) ? Ca[v] : Cb[v];
                float p = __expf(sv - mnew[st][v]);
                ps[st][v] += p;
                pbuf[((sk0 * 2 + st) * 64 + (q4 * 4 + v) + 16 * kq) * 8 + jj] = bf16_rn(p);
            }
        }
#pragma unroll
        for (int d = 1; d < 16; d <<= 1) {
#pragma unroll
            for (int v = 0; v < 4; v++) {
                ps[0][v] += __shfl_xor(ps[0][v], d, 16);
                ps[1][v] += __shfl_xor(ps[1][v], d, 16);
            }
        }
        if (l15 == 0) {
            *(f32x4*)&ssumb[(ch * 2 + 0) * 16 + q4 * 4] = ps[0];
            *(f32x4*)&ssumb[(ch * 2 + 1) * 16 + q4 * 4] = ps[1];
        }
        __syncthreads();   // B2
        f32x4 ts[2]; ts[0] = 0.f; ts[1] = 0.f;
#pragma unroll
        for (int cc = 0; cc < 8; cc++) {
            ts[0] += *(const f32x4*)&ssumb[(cc * 2 + 0) * 16 + q4 * 4];
            ts[1] += *(const f32x4*)&ssumb[(cc * 2 + 1) * 16 + q4 * 4];
        }
#pragma unroll
        for (int st = 0; st < 2; st++)
#pragma unroll
            for (int v = 0; v < 4; v++) l_run[st][v] = l_run[st][v] * alpha[st][v] + ts[st][v];
        // O rescale
#pragma unroll
        for (int st = 0; st < 2; st++)
#pragma unroll
            for (int ct = 0; ct < 4; ct++)
#pragma unroll
                for (int v = 0; v < 4; v++) O[st][ct][v] *= alpha[st][v];
        // P A-frags
        s16x8 pa[2][4];
#pragma unroll
        for (int st = 0; st < 2; st++)
#pragma unroll
            for (int sk = 0; sk < 4; sk++)
                pa[st][sk] = *(const s16x8*)&pbuf[((sk * 2 + st) * 64 + l) * 8];

        // prefetch next tile's kstep 0,1 K frags (live across barrier-free PV)
        if (tile < NT - 1) {
            const size_t b2 = (size_t)(tile * 128 + 128 + ch * 16 + l15) * RD + q4 * 8;
            khq[0] = *(const s16x8*)(Mhi + b2);
            klq[0] = *(const s16x8*)(Mlo + b2);
            khq[1] = *(const s16x8*)(Mhi + b2 + 32);
            klq[1] = *(const s16x8*)(Mlo + b2 + 32);
        }

        // ================= PV phase (no barriers) =================
#pragma unroll
        for (int ct = 0; ct < 4; ct++) {
            s16x8 btN[4];
            if (ct < 3) {
#pragma unroll
                for (int sk = 0; sk < 4; sk++)
                    btN[sk] = *(const s16x8*)(mtp + (size_t)(ct + 1) * 16 * NK + sk * 32);
            }
#pragma unroll
            for (int sk = 0; sk < 4; sk++) {
                O[0][ct] = __builtin_amdgcn_mfma_f32_16x16x32_bf16(pa[0][sk], btC[sk], O[0][ct], 0, 0, 0);
                O[1][ct] = __builtin_amdgcn_mfma_f32_16x16x32_bf16(pa[1][sk], btC[sk], O[1][ct], 0, 0, 0);
            }
            if (ct < 3) {
#pragma unroll
                for (int sk = 0; sk < 4; sk++) btC[sk] = btN[sk];
            }
        }
    }

    // ================= epilogue =================
#pragma unroll
    for (int st = 0; st < 2; st++)
#pragma unroll
        for (int ct = 0; ct < 4; ct++)
#pragma unroll
            for (int v = 0; v < 4; v++)
                out[(size_t)(qbase + st * 16 + q4 * 4 + v) * RD + (ch * 4 + ct) * 16 + l15] =
                    O[st][ct][v] / l_run[st][v];
}

// ---------------- fallback (ws too small): fp32, slow but exact ----------------
__global__ __launch_bounds__(256) void naive_kernel(const float* __restrict__ h,
                                                    const float* __restrict__ M,
                                                    float* __restrict__ out) {
    __shared__ float hs[16 * 520];
    __shared__ float ms[8 * 520];
    __shared__ float sdot[2][128];
    __shared__ float sm[16], sl[16], sal[16], sp[16][8];
    const int t = threadIdx.x;
    const int qbase = blockIdx.x * 16;
#pragma unroll
    for (int i = 0; i < 32; i++) {
        int e = t + i * 256;
        int row = e >> 9, col = e & 511;
        hs[row * 520 + col] = h[(size_t)(qbase + row) * RD + col];
    }
    if (t < 16) { sm[t] = -3e38f; sl[t] = 0.f; }
    float Oacc[32];
#pragma unroll
    for (int i = 0; i < 32; i++) Oacc[i] = 0.f;
    const int q = t >> 4;
    const int eb = (t & 15) * 32;

    for (int k0 = 0; k0 < NK; k0 += 8) {
        __syncthreads();
#pragma unroll
        for (int i = 0; i < 16; i++) {
            int e = t + i * 256;
            if (e < 4096) {
                int kk = e >> 9, col = e & 511;
                ms[kk * 520 + col] = M[(size_t)(k0 + kk) * RD + col];
            }
        }
        __syncthreads();
        {
            int pair = t & 127, half = t >> 7;
            int qq = pair & 15, kk = pair >> 4;
            const float* hp = &hs[qq * 520 + half * 256];
            const float* mp = &ms[kk * 520 + half * 256];
            float acc = 0.f;
#pragma unroll 8
            for (int e = 0; e < 256; e++) acc += hp[e] * mp[e];
            sdot[half][pair] = acc;
        }
        __syncthreads();
        if (t < 16) {
            int qq = t;
            float s8[8];
#pragma unroll
            for (int kk = 0; kk < 8; kk++) s8[kk] = sdot[0][qq + 16 * kk] + sdot[1][qq + 16 * kk];
            float mn = sm[qq];
#pragma unroll
            for (int kk = 0; kk < 8; kk++) mn = fmaxf(mn, s8[kk]);
            float al = __expf(sm[qq] - mn);
            float addl = 0.f;
#pragma unroll
            for (int kk = 0; kk < 8; kk++) { float p = __expf(s8[kk] - mn); sp[qq][kk] = p; addl += p; }
            sm[qq] = mn; sl[qq] = sl[qq] * al + addl; sal[qq] = al;
        }
        __syncthreads();
        {
            float al = sal[q];
#pragma unroll
            for (int i = 0; i < 32; i++) Oacc[i] *= al;
#pragma unroll
            for (int kk = 0; kk < 8; kk++) {
                float p = sp[q][kk];
                const float* mp = &ms[kk * 520 + eb];
#pragma unroll
                for (int i = 0; i < 32; i++) Oacc[i] += p * mp[i];
            }
        }
    }
    __syncthreads();
    float inv = 1.f / sl[q];
#pragma unroll
    for (int i = 0; i < 32; i++) out[(size_t)(qbase + q) * RD + eb + i] = Oacc[i] * inv;
}

extern "C" void kernel_launch(void* const* d_in, const int* in_sizes, int n_in,
                              void* d_out, int out_size, void* d_ws, size_t ws_size,
                              hipStream_t stream) {
    const float* h = (const float*)d_in[0];
    const float* M = (const float*)d_in[1];
    float* out = (float*)d_out;
    const size_t seg = (size_t)NK * RD;                      // u16 elems per converted buffer
    const size_t need = (seg * 3ull + 8192ull) * 2ull;       // Mhi+Mlo+MT + tail pad (bytes)

    if (ws_size >= need) {
        unsigned short* Mhi = (unsigned short*)d_ws;
        unsigned short* Mlo = Mhi + seg;
        unsigned short* MT  = Mlo + seg;
        preconv_kernel<<<dim3(313, 8), 256, 0, stream>>>(M, Mhi, Mlo, MT);
        flash3_kernel<<<256, 512, 0, stream>>>(h, Mhi, Mlo, MT, out);
    } else {
        naive_kernel<<<512, 256, 0, stream>>>(h, M, out);
    }
}

// Round 4
// 1831.798 us; speedup vs baseline: 1.5521x; 1.0144x over previous
//
#include <hip/hip_runtime.h>
#include <stdint.h>

#define NQ 8192
#define NK 20000
#define RD 512
#define KN 256          // keys per tile
#define NTT 79          // ceil(20000/256)
#define TS0 40          // split-0 tiles (keys 0..10239); split-1: 39 tiles (10240..20223, tail masked)

typedef float f32x4 __attribute__((ext_vector_type(4)));
typedef short s16x8 __attribute__((ext_vector_type(8)));

__device__ __forceinline__ unsigned short bf16_rn(float x) {
    uint32_t u = __float_as_uint(x);
    return (unsigned short)((u + 0x7FFFu + ((u >> 16) & 1)) >> 16);
}

// ---------------- preconv: M(fp32) -> Mhi (RTZ hi), Mlo (RN residual), MT (RN bf16, transposed) ----
__global__ void preconv_kernel(const float* __restrict__ M,
                               unsigned short* __restrict__ Mhi,
                               unsigned short* __restrict__ Mlo,
                               unsigned short* __restrict__ MT) {
    __shared__ float tilef[64 * 65];
    const int k0 = blockIdx.x * 64, r0 = blockIdx.y * 64;
    const int t = threadIdx.x;
#pragma unroll
    for (int i = 0; i < 16; i++) {
        int e = t + i * 256;
        int kr = e >> 6, cc = e & 63;
        int key = k0 + kr;
        if (key < NK) {
            float x = M[(size_t)key * RD + r0 + cc];
            uint32_t u = __float_as_uint(x);
            Mhi[(size_t)key * RD + r0 + cc] = (unsigned short)(u >> 16);
            Mlo[(size_t)key * RD + r0 + cc] = bf16_rn(x - __uint_as_float(u & 0xFFFF0000u));
            tilef[cc * 65 + kr] = x;
        }
    }
    __syncthreads();
#pragma unroll
    for (int i = 0; i < 16; i++) {
        int e = t + i * 256;
        int rr = e >> 6, kk = e & 63;
        int key = k0 + kk;
        if (key < NK) MT[(size_t)(r0 + rr) * NK + key] = bf16_rn(tilef[rr * 65 + kk]);
    }
}

// ---------------- flash kernel v4: BM=64, KN=256, split-K x2 ----------------
// 512 thr = 8 waves. wave ch covers keys ch*32 + cb*16 + l15 (cb=0,1); all 4 row-strips of 16.
// Per kstep: 24 MFMA vs 8 LDS A-reads vs 4 global K-loads (depth-2 pipeline). 4 barriers/tile.
// PV in two 128-key chunks (pbuf 16 KB); waves ch>=4 hold their P in regs until chunk 1.
__global__ __launch_bounds__(512, 2) void flash4_kernel(
        const float* __restrict__ h,
        const unsigned short* __restrict__ Mhi,
        const unsigned short* __restrict__ Mlo,
        const unsigned short* __restrict__ MT,
        float* __restrict__ out,
        float* __restrict__ Opart,
        float* __restrict__ mpart,
        float* __restrict__ lpart,
        int nsplit) {
    __shared__ unsigned short qbuf[2 * 32768];   // 128 KB: [hi|lo] x (4 strips x 16 steps) x 512 u16
    __shared__ unsigned short pbuf[16 * 512];    // 16 KB: one 128-key P chunk, 16 frags (sk*4+strip)
    __shared__ float smaxb[8 * 4 * 16];          // [ch][strip][row16]
    __shared__ float ssumb[8 * 4 * 16];

    const int tid = threadIdx.x;
    const int ch = tid >> 6, l = tid & 63;
    const int l15 = l & 15, q4 = l >> 4;
    const int kq = l15 >> 3, jj = l15 & 7;

    int qb, split;
    if (nsplit == 2) { qb = blockIdx.x & 127; split = blockIdx.x >> 7; }
    else             { qb = blockIdx.x;       split = 0; }
    const int koff = (split == 0) ? 0 : TS0 * KN;
    const int ntl  = (nsplit == 2) ? ((split == 0) ? TS0 : (NTT - TS0)) : NTT;
    const int qbase = qb * 64;

    // ---- stage Q -> LDS (hi RTZ / lo RN), frag-linear ----
#pragma unroll
    for (int i = 0; i < 8; i++) {
        int g = tid + i * 512;                  // 0..4095 = row*64 + s*4 + qg
        int row = g >> 6, s = (g >> 2) & 15, qg = g & 3;
        int strip = row >> 4, lrow = row & 15;
        const float* src = h + (size_t)(qbase + row) * RD + s * 32 + qg * 8;
        f32x4 a = *(const f32x4*)src;
        f32x4 b = *(const f32x4*)(src + 4);
        s16x8 hi8, lo8;
#pragma unroll
        for (int j = 0; j < 8; j++) {
            float x = (j < 4) ? a[j] : b[j - 4];
            uint32_t u = __float_as_uint(x);
            hi8[j] = (short)(u >> 16);
            lo8[j] = (short)bf16_rn(x - __uint_as_float(u & 0xFFFF0000u));
        }
        int off = ((strip * 16 + s) * 512 + (qg * 16 + lrow) * 8);
        *(s16x8*)&qbuf[off] = hi8;
        *(s16x8*)&qbuf[32768 + off] = lo8;
    }
    __syncthreads();

    f32x4 O[4][4];
#pragma unroll
    for (int st = 0; st < 4; st++)
#pragma unroll
        for (int ct = 0; ct < 4; ct++) O[st][ct] = 0.f;
    f32x4 m_run[4], l_run[4];
#pragma unroll
    for (int st = 0; st < 4; st++) { m_run[st] = -3e38f; l_run[st] = 0.f; }

    // K depth-2 pipeline regs: [cb][parity]
    s16x8 khq[2][2], klq[2][2];
    {
        const size_t b0 = (size_t)(koff + ch * 32 + l15) * RD + q4 * 8;
        const size_t b1 = b0 + (size_t)16 * RD;
        khq[0][0] = *(const s16x8*)(Mhi + b0);
        khq[0][1] = *(const s16x8*)(Mhi + b0 + 32);
        klq[0][0] = *(const s16x8*)(Mlo + b0);
        klq[0][1] = *(const s16x8*)(Mlo + b0 + 32);
        khq[1][0] = *(const s16x8*)(Mhi + b1);
        khq[1][1] = *(const s16x8*)(Mhi + b1 + 32);
        klq[1][0] = *(const s16x8*)(Mlo + b1);
        klq[1][1] = *(const s16x8*)(Mlo + b1 + 32);
    }

    for (int tile = 0; tile < ntl; tile++) {
        const size_t kbase0 = (size_t)(koff + tile * KN + ch * 32 + l15) * RD + q4 * 8;
        const size_t kbase1 = kbase0 + (size_t)16 * RD;

        // ================= S phase (no barriers, depth-2 pipeline) =================
        f32x4 C[4][2];
#pragma unroll
        for (int st = 0; st < 4; st++) { C[st][0] = 0.f; C[st][1] = 0.f; }
#pragma unroll
        for (int s = 0; s < 16; s++) {
            s16x8 kh0 = khq[0][s & 1], kl0 = klq[0][s & 1];
            s16x8 kh1 = khq[1][s & 1], kl1 = klq[1][s & 1];
            if (s < 14) {
                khq[0][s & 1] = *(const s16x8*)(Mhi + kbase0 + (s + 2) * 32);
                klq[0][s & 1] = *(const s16x8*)(Mlo + kbase0 + (s + 2) * 32);
                khq[1][s & 1] = *(const s16x8*)(Mhi + kbase1 + (s + 2) * 32);
                klq[1][s & 1] = *(const s16x8*)(Mlo + kbase1 + (s + 2) * 32);
            }
#pragma unroll
            for (int st = 0; st < 4; st++) {
                s16x8 qh = *(const s16x8*)&qbuf[(st * 16 + s) * 512 + l * 8];
                s16x8 ql = *(const s16x8*)&qbuf[32768 + (st * 16 + s) * 512 + l * 8];
                C[st][0] = __builtin_amdgcn_mfma_f32_16x16x32_bf16(qh, kh0, C[st][0], 0, 0, 0);
                C[st][1] = __builtin_amdgcn_mfma_f32_16x16x32_bf16(qh, kh1, C[st][1], 0, 0, 0);
                C[st][0] = __builtin_amdgcn_mfma_f32_16x16x32_bf16(ql, kh0, C[st][0], 0, 0, 0);
                C[st][1] = __builtin_amdgcn_mfma_f32_16x16x32_bf16(ql, kh1, C[st][1], 0, 0, 0);
                C[st][0] = __builtin_amdgcn_mfma_f32_16x16x32_bf16(qh, kl0, C[st][0], 0, 0, 0);
                C[st][1] = __builtin_amdgcn_mfma_f32_16x16x32_bf16(qh, kl1, C[st][1], 0, 0, 0);
            }
        }
        // mask tail keys (only last tile of split 1 / nsplit==1 can trigger)
        if (tile == ntl - 1) {
#pragma unroll
            for (int cb = 0; cb < 2; cb++) {
                int kg = koff + tile * KN + ch * 32 + cb * 16 + l15;
                if (kg >= NK) {
#pragma unroll
                    for (int st = 0; st < 4; st++) C[st][cb] = -3e38f;
                }
            }
        }

        // ================= softmax =================
        f32x4 mx[4];
#pragma unroll
        for (int st = 0; st < 4; st++) {
#pragma unroll
            for (int v = 0; v < 4; v++) mx[st][v] = fmaxf(C[st][0][v], C[st][1][v]);
        }
#pragma unroll
        for (int d = 1; d < 16; d <<= 1) {
#pragma unroll
            for (int st = 0; st < 4; st++)
#pragma unroll
                for (int v = 0; v < 4; v++) mx[st][v] = fmaxf(mx[st][v], __shfl_xor(mx[st][v], d, 16));
        }
        if (l15 == 0) {
#pragma unroll
            for (int st = 0; st < 4; st++) *(f32x4*)&smaxb[(ch * 4 + st) * 16 + q4 * 4] = mx[st];
        }
        __syncthreads();   // B1
        f32x4 mnew[4];
#pragma unroll
        for (int st = 0; st < 4; st++) mnew[st] = m_run[st];
#pragma unroll
        for (int cc = 0; cc < 8; cc++) {
#pragma unroll
            for (int st = 0; st < 4; st++) {
                f32x4 tv = *(const f32x4*)&smaxb[(cc * 4 + st) * 16 + q4 * 4];
#pragma unroll
                for (int v = 0; v < 4; v++) mnew[st][v] = fmaxf(mnew[st][v], tv[v]);
            }
        }
        f32x4 alpha[4];
#pragma unroll
        for (int st = 0; st < 4; st++)
#pragma unroll
            for (int v = 0; v < 4; v++) {
                alpha[st][v] = __expf(m_run[st][v] - mnew[st][v]);
                m_run[st][v] = mnew[st][v];
            }
        // p, partial sums; chunk0 (ch<4) -> pbuf now; chunk1 (ch>=4) kept packed in regs
        uint32_t pk[16];
        f32x4 ps[4];
#pragma unroll
        for (int st = 0; st < 4; st++) ps[st] = 0.f;
#pragma unroll
        for (int st = 0; st < 4; st++) {
#pragma unroll
            for (int cb = 0; cb < 2; cb++) {
#pragma unroll
                for (int v = 0; v < 4; v++) {
                    float p = __expf(C[st][cb][v] - mnew[st][v]);
                    ps[st][v] += p;
                    unsigned short pb = bf16_rn(p);
                    if (ch < 4) {
                        pbuf[(ch * 4 + st) * 512 + ((cb * 2 + kq) * 16 + q4 * 4 + v) * 8 + jj] = pb;
                    } else {
                        int pidx = (st * 2 + cb) * 2 + (v >> 1);
                        if (v & 1) pk[pidx] |= ((uint32_t)pb << 16);
                        else       pk[pidx] = pb;
                    }
                }
            }
        }
#pragma unroll
        for (int d = 1; d < 16; d <<= 1) {
#pragma unroll
            for (int st = 0; st < 4; st++)
#pragma unroll
                for (int v = 0; v < 4; v++) ps[st][v] += __shfl_xor(ps[st][v], d, 16);
        }
        if (l15 == 0) {
#pragma unroll
            for (int st = 0; st < 4; st++) *(f32x4*)&ssumb[(ch * 4 + st) * 16 + q4 * 4] = ps[st];
        }
        __syncthreads();   // B2 (ssumb + pbuf chunk0 visible)
        f32x4 ts[4];
#pragma unroll
        for (int st = 0; st < 4; st++) ts[st] = 0.f;
#pragma unroll
        for (int cc = 0; cc < 8; cc++) {
#pragma unroll
            for (int st = 0; st < 4; st++)
                ts[st] += *(const f32x4*)&ssumb[(cc * 4 + st) * 16 + q4 * 4];
        }
#pragma unroll
        for (int st = 0; st < 4; st++)
#pragma unroll
            for (int v = 0; v < 4; v++) l_run[st][v] = l_run[st][v] * alpha[st][v] + ts[st][v];
#pragma unroll
        for (int st = 0; st < 4; st++)
#pragma unroll
            for (int ct = 0; ct < 4; ct++)
#pragma unroll
                for (int v = 0; v < 4; v++) O[st][ct][v] *= alpha[st][v];

        // ================= PV chunk 0 (keys +0..127) =================
        const unsigned short* mtp = MT + (size_t)(ch * 64 + l15) * NK + koff + tile * KN;
        {
            s16x8 btC[4], btN[4], pa[4];
#pragma unroll
            for (int x = 0; x < 4; x++) btC[x] = *(const s16x8*)(mtp + (size_t)x * 16 * NK + q4 * 8);
#pragma unroll
            for (int sk = 0; sk < 4; sk++) {
                if (sk < 3) {
#pragma unroll
                    for (int x = 0; x < 4; x++)
                        btN[x] = *(const s16x8*)(mtp + (size_t)x * 16 * NK + (sk + 1) * 32 + q4 * 8);
                }
#pragma unroll
                for (int st = 0; st < 4; st++) pa[st] = *(const s16x8*)&pbuf[(sk * 4 + st) * 512 + l * 8];
#pragma unroll
                for (int ct = 0; ct < 4; ct++)
#pragma unroll
                    for (int st = 0; st < 4; st++)
                        O[st][ct] = __builtin_amdgcn_mfma_f32_16x16x32_bf16(pa[st], btC[ct], O[st][ct], 0, 0, 0);
                if (sk < 3) {
#pragma unroll
                    for (int x = 0; x < 4; x++) btC[x] = btN[x];
                }
            }
        }
        __syncthreads();   // B3 (chunk0 consumed)
        // write chunk1 P
        if (ch >= 4) {
#pragma unroll
            for (int st = 0; st < 4; st++)
#pragma unroll
                for (int cb = 0; cb < 2; cb++)
#pragma unroll
                    for (int v = 0; v < 4; v++) {
                        int pidx = (st * 2 + cb) * 2 + (v >> 1);
                        unsigned short pb = (v & 1) ? (unsigned short)(pk[pidx] >> 16)
                                                    : (unsigned short)(pk[pidx] & 0xFFFF);
                        pbuf[((ch - 4) * 4 + st) * 512 + ((cb * 2 + kq) * 16 + q4 * 4 + v) * 8 + jj] = pb;
                    }
        }
        // prefetch next tile's kstep 0,1 (consumed next S phase)
        if (tile < ntl - 1) {
            const size_t nb0 = (size_t)(koff + (tile + 1) * KN + ch * 32 + l15) * RD + q4 * 8;
            const size_t nb1 = nb0 + (size_t)16 * RD;
            khq[0][0] = *(const s16x8*)(Mhi + nb0);
            khq[0][1] = *(const s16x8*)(Mhi + nb0 + 32);
            klq[0][0] = *(const s16x8*)(Mlo + nb0);
            klq[0][1] = *(const s16x8*)(Mlo + nb0 + 32);
            khq[1][0] = *(const s16x8*)(Mhi + nb1);
            khq[1][1] = *(const s16x8*)(Mhi + nb1 + 32);
            klq[1][0] = *(const s16x8*)(Mlo + nb1);
            klq[1][1] = *(const s16x8*)(Mlo + nb1 + 32);
        }
        __syncthreads();   // B4 (chunk1 visible)
        // ================= PV chunk 1 (keys +128..255) =================
        {
            const unsigned short* mtp1 = mtp + 128;
            s16x8 btC[4], btN[4], pa[4];
#pragma unroll
            for (int x = 0; x < 4; x++) btC[x] = *(const s16x8*)(mtp1 + (size_t)x * 16 * NK + q4 * 8);
#pragma unroll
            for (int sk = 0; sk < 4; sk++) {
                if (sk < 3) {
#pragma unroll
                    for (int x = 0; x < 4; x++)
                        btN[x] = *(const s16x8*)(mtp1 + (size_t)x * 16 * NK + (sk + 1) * 32 + q4 * 8);
                }
#pragma unroll
                for (int st = 0; st < 4; st++) pa[st] = *(const s16x8*)&pbuf[(sk * 4 + st) * 512 + l * 8];
#pragma unroll
                for (int ct = 0; ct < 4; ct++)
#pragma unroll
                    for (int st = 0; st < 4; st++)
                        O[st][ct] = __builtin_amdgcn_mfma_f32_16x16x32_bf16(pa[st], btC[ct], O[st][ct], 0, 0, 0);
                if (sk < 3) {
#pragma unroll
                    for (int x = 0; x < 4; x++) btC[x] = btN[x];
                }
            }
        }
    }

    // ================= epilogue =================
    if (nsplit == 2) {
        float* Od = Opart + (size_t)split * NQ * RD;
#pragma unroll
        for (int st = 0; st < 4; st++)
#pragma unroll
            for (int ct = 0; ct < 4; ct++)
#pragma unroll
                for (int v = 0; v < 4; v++)
                    Od[(size_t)(qbase + st * 16 + q4 * 4 + v) * RD + (ch * 4 + ct) * 16 + l15] =
                        O[st][ct][v];
        if (ch == 0 && l15 == 0) {
#pragma unroll
            for (int st = 0; st < 4; st++)
#pragma unroll
                for (int v = 0; v < 4; v++) {
                    mpart[split * NQ + qbase + st * 16 + q4 * 4 + v] = m_run[st][v];
                    lpart[split * NQ + qbase + st * 16 + q4 * 4 + v] = l_run[st][v];
                }
        }
    } else {
#pragma unroll
        for (int st = 0; st < 4; st++)
#pragma unroll
            for (int ct = 0; ct < 4; ct++)
#pragma unroll
                for (int v = 0; v < 4; v++)
                    out[(size_t)(qbase + st * 16 + q4 * 4 + v) * RD + (ch * 4 + ct) * 16 + l15] =
                        O[st][ct][v] / l_run[st][v];
    }
}

// ---------------- combine split-K partials ----------------
__global__ __launch_bounds__(256) void combine_kernel(const float* __restrict__ Opart,
                                                      const float* __restrict__ mpart,
                                                      const float* __restrict__ lpart,
                                                      float* __restrict__ out) {
    const int t = threadIdx.x;
    const int row = blockIdx.x * 2 + (t >> 7);
    const int d = (t & 127) * 4;
    float m0 = mpart[row], m1 = mpart[NQ + row];
    float l0 = lpart[row], l1 = lpart[NQ + row];
    float m = fmaxf(m0, m1);
    float w0 = __expf(m0 - m), w1 = __expf(m1 - m);
    float inv = 1.f / (w0 * l0 + w1 * l1);
    f32x4 o0 = *(const f32x4*)&Opart[(size_t)row * RD + d];
    f32x4 o1 = *(const f32x4*)&Opart[(size_t)NQ * RD + (size_t)row * RD + d];
    f32x4 r;
#pragma unroll
    for (int v = 0; v < 4; v++) r[v] = (o0[v] * w0 + o1[v] * w1) * inv;
    *(f32x4*)&out[(size_t)row * RD + d] = r;
}

// ---------------- fallback (ws too small): fp32, slow but exact ----------------
__global__ __launch_bounds__(256) void naive_kernel(const float* __restrict__ h,
                                                    const float* __restrict__ M,
                                                    float* __restrict__ out) {
    __shared__ float hs[16 * 520];
    __shared__ float ms[8 * 520];
    __shared__ float sdot[2][128];
    __shared__ float sm[16], sl[16], sal[16], sp[16][8];
    const int t = threadIdx.x;
    const int qbase = blockIdx.x * 16;
#pragma unroll
    for (int i = 0; i < 32; i++) {
        int e = t + i * 256;
        int row = e >> 9, col = e & 511;
        hs[row * 520 + col] = h[(size_t)(qbase + row) * RD + col];
    }
    if (t < 16) { sm[t] = -3e38f; sl[t] = 0.f; }
    float Oacc[32];
#pragma unroll
    for (int i = 0; i < 32; i++) Oacc[i] = 0.f;
    const int q = t >> 4;
    const int eb = (t & 15) * 32;

    for (int k0 = 0; k0 < NK; k0 += 8) {
        __syncthreads();
#pragma unroll
        for (int i = 0; i < 16; i++) {
            int e = t + i * 256;
            if (e < 4096) {
                int kk = e >> 9, col = e & 511;
                ms[kk * 520 + col] = M[(size_t)(k0 + kk) * RD + col];
            }
        }
        __syncthreads();
        {
            int pair = t & 127, half = t >> 7;
            int qq = pair & 15, kk = pair >> 4;
            const float* hp = &hs[qq * 520 + half * 256];
            const float* mp = &ms[kk * 520 + half * 256];
            float acc = 0.f;
#pragma unroll 8
            for (int e = 0; e < 256; e++) acc += hp[e] * mp[e];
            sdot[half][pair] = acc;
        }
        __syncthreads();
        if (t < 16) {
            int qq = t;
            float s8[8];
#pragma unroll
            for (int kk = 0; kk < 8; kk++) s8[kk] = sdot[0][qq + 16 * kk] + sdot[1][qq + 16 * kk];
            float mn = sm[qq];
#pragma unroll
            for (int kk = 0; kk < 8; kk++) mn = fmaxf(mn, s8[kk]);
            float al = __expf(sm[qq] - mn);
            float addl = 0.f;
#pragma unroll
            for (int kk = 0; kk < 8; kk++) { float p = __expf(s8[kk] - mn); sp[qq][kk] = p; addl += p; }
            sm[qq] = mn; sl[qq] = sl[qq] * al + addl; sal[qq] = al;
        }
        __syncthreads();
        {
            float al = sal[q];
#pragma unroll
            for (int i = 0; i < 32; i++) Oacc[i] *= al;
#pragma unroll
            for (int kk = 0; kk < 8; kk++) {
                float p = sp[q][kk];
                const float* mp = &ms[kk * 520 + eb];
#pragma unroll
                for (int i = 0; i < 32; i++) Oacc[i] += p * mp[i];
            }
        }
    }
    __syncthreads();
    float inv = 1.f / sl[q];
#pragma unroll
    for (int i = 0; i < 32; i++) out[(size_t)(qbase + q) * RD + eb + i] = Oacc[i] * inv;
}

extern "C" void kernel_launch(void* const* d_in, const int* in_sizes, int n_in,
                              void* d_out, int out_size, void* d_ws, size_t ws_size,
                              hipStream_t stream) {
    const float* h = (const float*)d_in[0];
    const float* M = (const float*)d_in[1];
    float* out = (float*)d_out;
    const size_t seg = (size_t)NK * RD;                      // u16 elems per converted buffer
    // Mhi + Mlo + MT + 8K u16 pad (MT tail reads land here, 0xAA = finite bf16)
    const size_t base_bytes = (seg * 3ull + 8192ull) * 2ull;
    const size_t opart_bytes = 2ull * NQ * RD * 4ull;
    const size_t stat_bytes = 2ull * 2ull * NQ * 4ull;
    const size_t need_split = base_bytes + opart_bytes + stat_bytes;

    if (ws_size >= base_bytes) {
        unsigned short* Mhi = (unsigned short*)d_ws;
        unsigned short* Mlo = Mhi + seg;
        unsigned short* MT  = Mlo + seg;
        float* Opart = (float*)((char*)d_ws + base_bytes);
        float* mpart = Opart + 2ull * NQ * RD;
        float* lpart = mpart + 2ull * NQ;
        preconv_kernel<<<dim3(313, 8), 256, 0, stream>>>(M, Mhi, Mlo, MT);
        if (ws_size >= need_split) {
            flash4_kernel<<<256, 512, 0, stream>>>(h, Mhi, Mlo, MT, out, Opart, mpart, lpart, 2);
            combine_kernel<<<NQ / 2, 256, 0, stream>>>(Opart, mpart, lpart, out);
        } else {
            flash4_kernel<<<128, 512, 0, stream>>>(h, Mhi, Mlo, MT, out, Opart, mpart, lpart, 1);
        }
    } else {
        naive_kernel<<<512, 256, 0, stream>>>(h, M, out);
    }
}

// Round 5
// 1671.708 us; speedup vs baseline: 1.7007x; 1.0958x over previous
//
#include <hip/hip_runtime.h>
#include <stdint.h>

#define NQ 8192
#define NK 20000
#define RD 512
#define NT 157      // ceil(20000/128)
#define TS0 79      // split-0 tiles (keys 0..10111); split-1: 78 tiles (10112..20095, tail masked)

typedef float f32x4 __attribute__((ext_vector_type(4)));
typedef short s16x8 __attribute__((ext_vector_type(8)));

__device__ __forceinline__ unsigned short bf16_rn(float x) {
    uint32_t u = __float_as_uint(x);
    return (unsigned short)((u + 0x7FFFu + ((u >> 16) & 1)) >> 16);
}

// ---------------- preconv: M(fp32) -> Mhi (RTZ hi), Mlo (RN residual), MT (RN bf16, transposed) ----
__global__ void preconv_kernel(const float* __restrict__ M,
                               unsigned short* __restrict__ Mhi,
                               unsigned short* __restrict__ Mlo,
                               unsigned short* __restrict__ MT) {
    __shared__ float tilef[64 * 65];
    const int k0 = blockIdx.x * 64, r0 = blockIdx.y * 64;
    const int t = threadIdx.x;
#pragma unroll
    for (int i = 0; i < 16; i++) {
        int e = t + i * 256;
        int kr = e >> 6, cc = e & 63;
        int key = k0 + kr;
        if (key < NK) {
            float x = M[(size_t)key * RD + r0 + cc];
            uint32_t u = __float_as_uint(x);
            Mhi[(size_t)key * RD + r0 + cc] = (unsigned short)(u >> 16);
            Mlo[(size_t)key * RD + r0 + cc] = bf16_rn(x - __uint_as_float(u & 0xFFFF0000u));
            tilef[cc * 65 + kr] = x;
        }
    }
    __syncthreads();
#pragma unroll
    for (int i = 0; i < 16; i++) {
        int e = t + i * 256;
        int rr = e >> 6, kk = e & 63;
        int key = k0 + kk;
        if (key < NK) MT[(size_t)(r0 + rr) * NK + key] = bf16_rn(tilef[rr * 65 + kk]);
    }
}

// ---------------- flash kernel v5: 4-wave blocks, 2 blocks/CU, split-K x2 ----------------
// Block: 256 thr = 4 waves, BM=32 rows, KN=128 keys/tile. Wave ch covers keys
// ch*32 + cb*16 + l15 (cb=0,1), both 16-row strips; PV: output cols ch*128..+127.
// Q (hi/lo) in LDS frag-linear (64 KB); K global->VGPR depth-2 pipeline; 2 barriers/tile.
// LDS 73 KB -> 2 blocks/CU = two independent barrier domains (latency cover).
// split = blockIdx&1 -> each XCD hosts one split only (pure L2 convoy stream).
__global__ __launch_bounds__(256, 2) void flash5_kernel(
        const float* __restrict__ h,
        const unsigned short* __restrict__ Mhi,
        const unsigned short* __restrict__ Mlo,
        const unsigned short* __restrict__ MT,
        float* __restrict__ out,
        float* __restrict__ Opart,
        float* __restrict__ mpart,
        float* __restrict__ lpart,
        int nsplit) {
    __shared__ unsigned short qbuf[32768];   // 64 KB: [hi|lo] x (2 strips x 16 steps) x 512 u16
    __shared__ unsigned short pbuf[8 * 512]; // 8 KB: P frags (sk(=ch)*2 + strip)
    __shared__ float smaxb[4 * 2 * 16];      // [ch][strip][row16]
    __shared__ float ssumb[4 * 2 * 16];

    const int tid = threadIdx.x;
    const int ch = tid >> 6, l = tid & 63;
    const int l15 = l & 15, q4 = l >> 4;
    const int kq = (l15 >> 3) & 1, jj = l15 & 7;

    int qb, split;
    if (nsplit == 2) { split = blockIdx.x & 1; qb = blockIdx.x >> 1; }
    else             { split = 0;              qb = blockIdx.x; }
    const int koff = (split == 0) ? 0 : TS0 * 128;
    const int ntl  = (nsplit == 2) ? ((split == 0) ? TS0 : (NT - TS0)) : NT;
    const int qbase = qb * 32;

    // ---- stage Q -> LDS (hi RTZ / lo RN), frag-linear ----
#pragma unroll
    for (int i = 0; i < 8; i++) {
        int g = tid + i * 256;                  // 0..2047 = row*64 + s*4 + qg
        int row = g >> 6, s = (g >> 2) & 15, qg = g & 3;
        int strip = row >> 4, lrow = row & 15;
        const float* src = h + (size_t)(qbase + row) * RD + s * 32 + qg * 8;
        f32x4 a = *(const f32x4*)src;
        f32x4 b = *(const f32x4*)(src + 4);
        s16x8 hi8, lo8;
#pragma unroll
        for (int j = 0; j < 8; j++) {
            float x = (j < 4) ? a[j] : b[j - 4];
            uint32_t u = __float_as_uint(x);
            hi8[j] = (short)(u >> 16);
            lo8[j] = (short)bf16_rn(x - __uint_as_float(u & 0xFFFF0000u));
        }
        int off = ((strip * 16 + s) * 512 + (qg * 16 + lrow) * 8);
        *(s16x8*)&qbuf[off] = hi8;
        *(s16x8*)&qbuf[16384 + off] = lo8;
    }
    __syncthreads();

    f32x4 O[2][8];
#pragma unroll
    for (int st = 0; st < 2; st++)
#pragma unroll
        for (int ct = 0; ct < 8; ct++) O[st][ct] = 0.f;
    f32x4 m_run[2], l_run[2];
    m_run[0] = -3e38f; m_run[1] = -3e38f; l_run[0] = 0.f; l_run[1] = 0.f;

    // K depth-2 pipeline regs: [cb][parity]
    s16x8 khq[2][2], klq[2][2];
    {
        const size_t b0 = (size_t)(koff + ch * 32 + l15) * RD + q4 * 8;
        const size_t b1 = b0 + (size_t)16 * RD;
        khq[0][0] = *(const s16x8*)(Mhi + b0);
        khq[0][1] = *(const s16x8*)(Mhi + b0 + 32);
        klq[0][0] = *(const s16x8*)(Mlo + b0);
        klq[0][1] = *(const s16x8*)(Mlo + b0 + 32);
        khq[1][0] = *(const s16x8*)(Mhi + b1);
        khq[1][1] = *(const s16x8*)(Mhi + b1 + 32);
        klq[1][0] = *(const s16x8*)(Mlo + b1);
        klq[1][1] = *(const s16x8*)(Mlo + b1 + 32);
    }

    for (int tile = 0; tile < ntl; tile++) {
        const size_t kbase0 = (size_t)(koff + tile * 128 + ch * 32 + l15) * RD + q4 * 8;
        const size_t kbase1 = kbase0 + (size_t)16 * RD;

        // ================= S phase (no barriers, depth-2 pipeline) =================
        f32x4 C[2][2];
        C[0][0] = 0.f; C[0][1] = 0.f; C[1][0] = 0.f; C[1][1] = 0.f;
#pragma unroll
        for (int s = 0; s < 16; s++) {
            s16x8 kh0 = khq[0][s & 1], kl0 = klq[0][s & 1];
            s16x8 kh1 = khq[1][s & 1], kl1 = klq[1][s & 1];
            if (s < 14) {
                khq[0][s & 1] = *(const s16x8*)(Mhi + kbase0 + (s + 2) * 32);
                klq[0][s & 1] = *(const s16x8*)(Mlo + kbase0 + (s + 2) * 32);
                khq[1][s & 1] = *(const s16x8*)(Mhi + kbase1 + (s + 2) * 32);
                klq[1][s & 1] = *(const s16x8*)(Mlo + kbase1 + (s + 2) * 32);
            }
#pragma unroll
            for (int st = 0; st < 2; st++) {
                s16x8 qh = *(const s16x8*)&qbuf[(st * 16 + s) * 512 + l * 8];
                s16x8 ql = *(const s16x8*)&qbuf[16384 + (st * 16 + s) * 512 + l * 8];
                C[st][0] = __builtin_amdgcn_mfma_f32_16x16x32_bf16(qh, kh0, C[st][0], 0, 0, 0);
                C[st][1] = __builtin_amdgcn_mfma_f32_16x16x32_bf16(qh, kh1, C[st][1], 0, 0, 0);
                C[st][0] = __builtin_amdgcn_mfma_f32_16x16x32_bf16(ql, kh0, C[st][0], 0, 0, 0);
                C[st][1] = __builtin_amdgcn_mfma_f32_16x16x32_bf16(ql, kh1, C[st][1], 0, 0, 0);
                C[st][0] = __builtin_amdgcn_mfma_f32_16x16x32_bf16(qh, kl0, C[st][0], 0, 0, 0);
                C[st][1] = __builtin_amdgcn_mfma_f32_16x16x32_bf16(qh, kl1, C[st][1], 0, 0, 0);
            }
        }
        // mask tail keys
        if (tile == ntl - 1) {
#pragma unroll
            for (int cb = 0; cb < 2; cb++) {
                int kg = koff + tile * 128 + ch * 32 + cb * 16 + l15;
                if (kg >= NK) { C[0][cb] = -3e38f; C[1][cb] = -3e38f; }
            }
        }

        // ================= softmax =================
        f32x4 mx[2];
#pragma unroll
        for (int st = 0; st < 2; st++)
#pragma unroll
            for (int v = 0; v < 4; v++) mx[st][v] = fmaxf(C[st][0][v], C[st][1][v]);
#pragma unroll
        for (int d = 1; d < 16; d <<= 1) {
#pragma unroll
            for (int st = 0; st < 2; st++)
#pragma unroll
                for (int v = 0; v < 4; v++) mx[st][v] = fmaxf(mx[st][v], __shfl_xor(mx[st][v], d, 16));
        }
        if (l15 == 0) {
            *(f32x4*)&smaxb[(ch * 2 + 0) * 16 + q4 * 4] = mx[0];
            *(f32x4*)&smaxb[(ch * 2 + 1) * 16 + q4 * 4] = mx[1];
        }
        __syncthreads();   // B1
        f32x4 mnew[2]; mnew[0] = m_run[0]; mnew[1] = m_run[1];
#pragma unroll
        for (int cc = 0; cc < 4; cc++) {
#pragma unroll
            for (int st = 0; st < 2; st++) {
                f32x4 tv = *(const f32x4*)&smaxb[(cc * 2 + st) * 16 + q4 * 4];
#pragma unroll
                for (int v = 0; v < 4; v++) mnew[st][v] = fmaxf(mnew[st][v], tv[v]);
            }
        }
        f32x4 alpha[2];
#pragma unroll
        for (int st = 0; st < 2; st++)
#pragma unroll
            for (int v = 0; v < 4; v++) {
                alpha[st][v] = __expf(m_run[st][v] - mnew[st][v]);
                m_run[st][v] = mnew[st][v];
            }
        // p + pbuf write + partial sums (wave ch == k-group sk)
        f32x4 ps[2]; ps[0] = 0.f; ps[1] = 0.f;
#pragma unroll
        for (int st = 0; st < 2; st++) {
#pragma unroll
            for (int cb = 0; cb < 2; cb++) {
#pragma unroll
                for (int v = 0; v < 4; v++) {
                    float p = __expf(C[st][cb][v] - mnew[st][v]);
                    ps[st][v] += p;
                    pbuf[(ch * 2 + st) * 512 + ((cb * 2 + kq) * 16 + q4 * 4 + v) * 8 + jj] = bf16_rn(p);
                }
            }
        }
#pragma unroll
        for (int d = 1; d < 16; d <<= 1) {
#pragma unroll
            for (int st = 0; st < 2; st++)
#pragma unroll
                for (int v = 0; v < 4; v++) ps[st][v] += __shfl_xor(ps[st][v], d, 16);
        }
        if (l15 == 0) {
            *(f32x4*)&ssumb[(ch * 2 + 0) * 16 + q4 * 4] = ps[0];
            *(f32x4*)&ssumb[(ch * 2 + 1) * 16 + q4 * 4] = ps[1];
        }
        __syncthreads();   // B2 (ssumb + pbuf visible)
        f32x4 ts[2]; ts[0] = 0.f; ts[1] = 0.f;
#pragma unroll
        for (int cc = 0; cc < 4; cc++) {
            ts[0] += *(const f32x4*)&ssumb[(cc * 2 + 0) * 16 + q4 * 4];
            ts[1] += *(const f32x4*)&ssumb[(cc * 2 + 1) * 16 + q4 * 4];
        }
#pragma unroll
        for (int st = 0; st < 2; st++)
#pragma unroll
            for (int v = 0; v < 4; v++) l_run[st][v] = l_run[st][v] * alpha[st][v] + ts[st][v];
#pragma unroll
        for (int st = 0; st < 2; st++)
#pragma unroll
            for (int ct = 0; ct < 8; ct++)
#pragma unroll
                for (int v = 0; v < 4; v++) O[st][ct][v] *= alpha[st][v];
        // P A-frags (all 4 k-groups)
        s16x8 pa[2][4];
#pragma unroll
        for (int st = 0; st < 2; st++)
#pragma unroll
            for (int sk = 0; sk < 4; sk++)
                pa[st][sk] = *(const s16x8*)&pbuf[((sk * 2 + st) * 512) + l * 8];

        // prefetch next tile's kstep 0,1 (live across barrier-free PV)
        if (tile < ntl - 1) {
            const size_t nb0 = (size_t)(koff + (tile + 1) * 128 + ch * 32 + l15) * RD + q4 * 8;
            const size_t nb1 = nb0 + (size_t)16 * RD;
            khq[0][0] = *(const s16x8*)(Mhi + nb0);
            khq[0][1] = *(const s16x8*)(Mhi + nb0 + 32);
            klq[0][0] = *(const s16x8*)(Mlo + nb0);
            klq[0][1] = *(const s16x8*)(Mlo + nb0 + 32);
            khq[1][0] = *(const s16x8*)(Mhi + nb1);
            khq[1][1] = *(const s16x8*)(Mhi + nb1 + 32);
            klq[1][0] = *(const s16x8*)(Mlo + nb1);
            klq[1][1] = *(const s16x8*)(Mlo + nb1 + 32);
        }

        // ================= PV phase (no barriers); wave ch -> out cols ch*128..+127 ========
        const unsigned short* mtp = MT + (size_t)(ch * 128 + l15) * NK + koff + tile * 128 + q4 * 8;
#pragma unroll
        for (int ct = 0; ct < 8; ct++) {
            s16x8 btC[4];
#pragma unroll
            for (int sk = 0; sk < 4; sk++)
                btC[sk] = *(const s16x8*)(mtp + (size_t)ct * 16 * NK + sk * 32);
#pragma unroll
            for (int sk = 0; sk < 4; sk++) {
                O[0][ct] = __builtin_amdgcn_mfma_f32_16x16x32_bf16(pa[0][sk], btC[sk], O[0][ct], 0, 0, 0);
                O[1][ct] = __builtin_amdgcn_mfma_f32_16x16x32_bf16(pa[1][sk], btC[sk], O[1][ct], 0, 0, 0);
            }
        }
    }

    // ================= epilogue =================
    if (nsplit == 2) {
        float* Od = Opart + (size_t)split * NQ * RD;
#pragma unroll
        for (int st = 0; st < 2; st++)
#pragma unroll
            for (int ct = 0; ct < 8; ct++)
#pragma unroll
                for (int v = 0; v < 4; v++)
                    Od[(size_t)(qbase + st * 16 + q4 * 4 + v) * RD + ch * 128 + ct * 16 + l15] =
                        O[st][ct][v];
        if (ch == 0 && l15 == 0) {
#pragma unroll
            for (int st = 0; st < 2; st++)
#pragma unroll
                for (int v = 0; v < 4; v++) {
                    mpart[split * NQ + qbase + st * 16 + q4 * 4 + v] = m_run[st][v];
                    lpart[split * NQ + qbase + st * 16 + q4 * 4 + v] = l_run[st][v];
                }
        }
    } else {
#pragma unroll
        for (int st = 0; st < 2; st++)
#pragma unroll
            for (int ct = 0; ct < 8; ct++)
#pragma unroll
                for (int v = 0; v < 4; v++)
                    out[(size_t)(qbase + st * 16 + q4 * 4 + v) * RD + ch * 128 + ct * 16 + l15] =
                        O[st][ct][v] / l_run[st][v];
    }
}

// ---------------- combine split-K partials ----------------
__global__ __launch_bounds__(256) void combine_kernel(const float* __restrict__ Opart,
                                                      const float* __restrict__ mpart,
                                                      const float* __restrict__ lpart,
                                                      float* __restrict__ out) {
    const int t = threadIdx.x;
    const int row = blockIdx.x * 2 + (t >> 7);
    const int d = (t & 127) * 4;
    float m0 = mpart[row], m1 = mpart[NQ + row];
    float l0 = lpart[row], l1 = lpart[NQ + row];
    float m = fmaxf(m0, m1);
    float w0 = __expf(m0 - m), w1 = __expf(m1 - m);
    float inv = 1.f / (w0 * l0 + w1 * l1);
    f32x4 o0 = *(const f32x4*)&Opart[(size_t)row * RD + d];
    f32x4 o1 = *(const f32x4*)&Opart[(size_t)NQ * RD + (size_t)row * RD + d];
    f32x4 r;
#pragma unroll
    for (int v = 0; v < 4; v++) r[v] = (o0[v] * w0 + o1[v] * w1) * inv;
    *(f32x4*)&out[(size_t)row * RD + d] = r;
}

// ---------------- fallback (ws too small): fp32, slow but exact ----------------
__global__ __launch_bounds__(256) void naive_kernel(const float* __restrict__ h,
                                                    const float* __restrict__ M,
                                                    float* __restrict__ out) {
    __shared__ float hs[16 * 520];
    __shared__ float ms[8 * 520];
    __shared__ float sdot[2][128];
    __shared__ float sm[16], sl[16], sal[16], sp[16][8];
    const int t = threadIdx.x;
    const int qbase = blockIdx.x * 16;
#pragma unroll
    for (int i = 0; i < 32; i++) {
        int e = t + i * 256;
        int row = e >> 9, col = e & 511;
        hs[row * 520 + col] = h[(size_t)(qbase + row) * RD + col];
    }
    if (t < 16) { sm[t] = -3e38f; sl[t] = 0.f; }
    float Oacc[32];
#pragma unroll
    for (int i = 0; i < 32; i++) Oacc[i] = 0.f;
    const int q = t >> 4;
    const int eb = (t & 15) * 32;

    for (int k0 = 0; k0 < NK; k0 += 8) {
        __syncthreads();
#pragma unroll
        for (int i = 0; i < 16; i++) {
            int e = t + i * 256;
            if (e < 4096) {
                int kk = e >> 9, col = e & 511;
                ms[kk * 520 + col] = M[(size_t)(k0 + kk) * RD + col];
            }
        }
        __syncthreads();
        {
            int pair = t & 127, half = t >> 7;
            int qq = pair & 15, kk = pair >> 4;
            const float* hp = &hs[qq * 520 + half * 256];
            const float* mp = &ms[kk * 520 + half * 256];
            float acc = 0.f;
#pragma unroll 8
            for (int e = 0; e < 256; e++) acc += hp[e] * mp[e];
            sdot[half][pair] = acc;
        }
        __syncthreads();
        if (t < 16) {
            int qq = t;
            float s8[8];
#pragma unroll
            for (int kk = 0; kk < 8; kk++) s8[kk] = sdot[0][qq + 16 * kk] + sdot[1][qq + 16 * kk];
            float mn = sm[qq];
#pragma unroll
            for (int kk = 0; kk < 8; kk++) mn = fmaxf(mn, s8[kk]);
            float al = __expf(sm[qq] - mn);
            float addl = 0.f;
#pragma unroll
            for (int kk = 0; kk < 8; kk++) { float p = __expf(s8[kk] - mn); sp[qq][kk] = p; addl += p; }
            sm[qq] = mn; sl[qq] = sl[qq] * al + addl; sal[qq] = al;
        }
        __syncthreads();
        {
            float al = sal[q];
#pragma unroll
            for (int i = 0; i < 32; i++) Oacc[i] *= al;
#pragma unroll
            for (int kk = 0; kk < 8; kk++) {
                float p = sp[q][kk];
                const float* mp = &ms[kk * 520 + eb];
#pragma unroll
                for (int i = 0; i < 32; i++) Oacc[i] += p * mp[i];
            }
        }
    }
    __syncthreads();
    float inv = 1.f / sl[q];
#pragma unroll
    for (int i = 0; i < 32; i++) out[(size_t)(qbase + q) * RD + eb + i] = Oacc[i] * inv;
}

extern "C" void kernel_launch(void* const* d_in, const int* in_sizes, int n_in,
                              void* d_out, int out_size, void* d_ws, size_t ws_size,
                              hipStream_t stream) {
    const float* h = (const float*)d_in[0];
    const float* M = (const float*)d_in[1];
    float* out = (float*)d_out;
    const size_t seg = (size_t)NK * RD;                      // u16 elems per converted buffer
    // Mhi + Mlo + MT + 8K u16 pad (tail reads stay in d_ws; 0xAA poison = finite bf16)
    const size_t base_bytes = (seg * 3ull + 8192ull) * 2ull;
    const size_t opart_bytes = 2ull * NQ * RD * 4ull;
    const size_t stat_bytes = 2ull * 2ull * NQ * 4ull;
    const size_t need_split = base_bytes + opart_bytes + stat_bytes;

    if (ws_size >= base_bytes) {
        unsigned short* Mhi = (unsigned short*)d_ws;
        unsigned short* Mlo = Mhi + seg;
        unsigned short* MT  = Mlo + seg;
        float* Opart = (float*)((char*)d_ws + base_bytes);
        float* mpart = Opart + 2ull * NQ * RD;
        float* lpart = mpart + 2ull * NQ;
        preconv_kernel<<<dim3(313, 8), 256, 0, stream>>>(M, Mhi, Mlo, MT);
        if (ws_size >= need_split) {
            flash5_kernel<<<512, 256, 0, stream>>>(h, Mhi, Mlo, MT, out, Opart, mpart, lpart, 2);
            combine_kernel<<<NQ / 2, 256, 0, stream>>>(Opart, mpart, lpart, out);
        } else {
            flash5_kernel<<<256, 256, 0, stream>>>(h, Mhi, Mlo, MT, out, Opart, mpart, lpart, 1);
        }
    } else {
        naive_kernel<<<512, 256, 0, stream>>>(h, M, out);
    }
}

// Round 6
// 1588.027 us; speedup vs baseline: 1.7903x; 1.0527x over previous
//
#include <hip/hip_runtime.h>
#include <stdint.h>

#define NQ 8192
#define NK 20000
#define RD 512
#define NT 157      // ceil(20000/128)
#define TS0 79      // split-0 tiles (keys 0..10111); split-1: 78 tiles (10112..20095, tail masked)

typedef float f32x4 __attribute__((ext_vector_type(4)));
typedef short s16x8 __attribute__((ext_vector_type(8)));

__device__ __forceinline__ unsigned short bf16_rn(float x) {
    uint32_t u = __float_as_uint(x);
    return (unsigned short)((u + 0x7FFFu + ((u >> 16) & 1)) >> 16);
}

// workgroup barrier that waits ONLY on LDS ops -- global loads stay in flight
// (plain __syncthreads() emits s_waitcnt vmcnt(0) which drains our prefetch pipeline)
__device__ __forceinline__ void lds_barrier() {
    asm volatile("s_waitcnt lgkmcnt(0)\n\ts_barrier" ::: "memory");
}

// ---------------- preconv: M(fp32) -> Mhi (RTZ hi), Mlo (RN residual), MT (RN bf16, transposed) ----
__global__ void preconv_kernel(const float* __restrict__ M,
                               unsigned short* __restrict__ Mhi,
                               unsigned short* __restrict__ Mlo,
                               unsigned short* __restrict__ MT) {
    __shared__ float tilef[64 * 65];
    const int k0 = blockIdx.x * 64, r0 = blockIdx.y * 64;
    const int t = threadIdx.x;
#pragma unroll
    for (int i = 0; i < 16; i++) {
        int e = t + i * 256;
        int kr = e >> 6, cc = e & 63;
        int key = k0 + kr;
        if (key < NK) {
            float x = M[(size_t)key * RD + r0 + cc];
            uint32_t u = __float_as_uint(x);
            Mhi[(size_t)key * RD + r0 + cc] = (unsigned short)(u >> 16);
            Mlo[(size_t)key * RD + r0 + cc] = bf16_rn(x - __uint_as_float(u & 0xFFFF0000u));
            tilef[cc * 65 + kr] = x;
        }
    }
    __syncthreads();
#pragma unroll
    for (int i = 0; i < 16; i++) {
        int e = t + i * 256;
        int rr = e >> 6, kk = e & 63;
        int key = k0 + kk;
        if (key < NK) MT[(size_t)(r0 + rr) * NK + key] = bf16_rn(tilef[rr * 65 + kk]);
    }
}

// ---------------- flash kernel v6: lds-only barriers + deep cross-tile pipelines --------------
// Shape = flash5 (proven no-spill): 256 thr = 4 waves, BM=32, KN=128, 2 blocks/CU, split-K x2.
// New: (1) barriers wait lgkmcnt only -> global prefetches survive them;
//      (2) K pipeline depth 4 on global kstep stream, wraps across tiles;
//      (3) PV B-frag depth-2 pipeline, ct0/ct1 issued before softmax.
__global__ __launch_bounds__(256, 2) void flash6_kernel(
        const float* __restrict__ h,
        const unsigned short* __restrict__ Mhi,
        const unsigned short* __restrict__ Mlo,
        const unsigned short* __restrict__ MT,
        float* __restrict__ out,
        float* __restrict__ Opart,
        float* __restrict__ mpart,
        float* __restrict__ lpart,
        int nsplit) {
    __shared__ unsigned short qbuf[32768];   // 64 KB: [hi|lo] x (2 strips x 16 steps) x 512 u16
    __shared__ unsigned short pbuf[8 * 512]; // 8 KB: P frags (sk*2 + strip)
    __shared__ float smaxb[4 * 2 * 16];      // [ch][strip][row16]
    __shared__ float ssumb[4 * 2 * 16];

    const int tid = threadIdx.x;
    const int ch = tid >> 6, l = tid & 63;
    const int l15 = l & 15, q4 = l >> 4;
    const int kq = (l15 >> 3) & 1, jj = l15 & 7;

    int qb, split;
    if (nsplit == 2) { split = blockIdx.x & 1; qb = blockIdx.x >> 1; }
    else             { split = 0;              qb = blockIdx.x; }
    const int koff = (split == 0) ? 0 : TS0 * 128;
    const int ntl  = (nsplit == 2) ? ((split == 0) ? TS0 : (NT - TS0)) : NT;
    const int total_ks = ntl * 16;
    const int qbase = qb * 32;

    // per-wave constant piece of every K address
    const size_t base_w = (size_t)(ch * 32 + l15) * RD + q4 * 8;
    auto kaddr = [&](int g, int cb) -> size_t {   // g = global kstep index (tile*16 + s)
        if (g >= total_ks) g = total_ks - 1;      // clamp: harmless reload of last kstep
        int t2 = g >> 4, s2 = g & 15;
        return (size_t)(koff + t2 * 128) * RD + (size_t)s2 * 32 + base_w + (size_t)cb * (16 * RD);
    };

    // ---- prime K pipeline depth 4 (in flight during Q staging) ----
    s16x8 kh[2][4], kl[2][4];
#pragma unroll
    for (int i = 0; i < 4; i++) {
        size_t a0 = kaddr(i, 0), a1 = kaddr(i, 1);
        kh[0][i] = *(const s16x8*)(Mhi + a0);
        kl[0][i] = *(const s16x8*)(Mlo + a0);
        kh[1][i] = *(const s16x8*)(Mhi + a1);
        kl[1][i] = *(const s16x8*)(Mlo + a1);
    }

    // ---- stage Q -> LDS (hi RTZ / lo RN), frag-linear ----
#pragma unroll
    for (int i = 0; i < 8; i++) {
        int g = tid + i * 256;                  // 0..2047 = row*64 + s*4 + qg
        int row = g >> 6, s = (g >> 2) & 15, qg = g & 3;
        int strip = row >> 4, lrow = row & 15;
        const float* src = h + (size_t)(qbase + row) * RD + s * 32 + qg * 8;
        f32x4 a = *(const f32x4*)src;
        f32x4 b = *(const f32x4*)(src + 4);
        s16x8 hi8, lo8;
#pragma unroll
        for (int j = 0; j < 8; j++) {
            float x = (j < 4) ? a[j] : b[j - 4];
            uint32_t u = __float_as_uint(x);
            hi8[j] = (short)(u >> 16);
            lo8[j] = (short)bf16_rn(x - __uint_as_float(u & 0xFFFF0000u));
        }
        int off = ((strip * 16 + s) * 512 + (qg * 16 + lrow) * 8);
        *(s16x8*)&qbuf[off] = hi8;
        *(s16x8*)&qbuf[16384 + off] = lo8;
    }
    lds_barrier();      // qbuf visible; K prime stays in flight

    f32x4 O[2][8];
#pragma unroll
    for (int st = 0; st < 2; st++)
#pragma unroll
        for (int ct = 0; ct < 8; ct++) O[st][ct] = 0.f;
    f32x4 m_run[2], l_run[2];
    m_run[0] = -3e38f; m_run[1] = -3e38f; l_run[0] = 0.f; l_run[1] = 0.f;

    for (int tile = 0; tile < ntl; tile++) {
        // ================= S phase: depth-4 pipeline, prefetch wraps into next tile ==========
        f32x4 C[2][2];
        C[0][0] = 0.f; C[0][1] = 0.f; C[1][0] = 0.f; C[1][1] = 0.f;
#pragma unroll
        for (int s = 0; s < 16; s++) {
            const int sl = s & 3;
            s16x8 kh0 = kh[0][sl], kl0 = kl[0][sl];
            s16x8 kh1 = kh[1][sl], kl1 = kl[1][sl];
            {   // refill slot with kstep s+4 (crosses into next tile for s>=12)
                int g = tile * 16 + s + 4;
                size_t a0 = kaddr(g, 0), a1 = kaddr(g, 1);
                kh[0][sl] = *(const s16x8*)(Mhi + a0);
                kl[0][sl] = *(const s16x8*)(Mlo + a0);
                kh[1][sl] = *(const s16x8*)(Mhi + a1);
                kl[1][sl] = *(const s16x8*)(Mlo + a1);
            }
#pragma unroll
            for (int st = 0; st < 2; st++) {
                s16x8 qh = *(const s16x8*)&qbuf[(st * 16 + s) * 512 + l * 8];
                s16x8 ql = *(const s16x8*)&qbuf[16384 + (st * 16 + s) * 512 + l * 8];
                C[st][0] = __builtin_amdgcn_mfma_f32_16x16x32_bf16(qh, kh0, C[st][0], 0, 0, 0);
                C[st][1] = __builtin_amdgcn_mfma_f32_16x16x32_bf16(qh, kh1, C[st][1], 0, 0, 0);
                C[st][0] = __builtin_amdgcn_mfma_f32_16x16x32_bf16(ql, kh0, C[st][0], 0, 0, 0);
                C[st][1] = __builtin_amdgcn_mfma_f32_16x16x32_bf16(ql, kh1, C[st][1], 0, 0, 0);
                C[st][0] = __builtin_amdgcn_mfma_f32_16x16x32_bf16(qh, kl0, C[st][0], 0, 0, 0);
                C[st][1] = __builtin_amdgcn_mfma_f32_16x16x32_bf16(qh, kl1, C[st][1], 0, 0, 0);
            }
        }
        // mask tail keys
        if (tile == ntl - 1) {
#pragma unroll
            for (int cb = 0; cb < 2; cb++) {
                int kg = koff + tile * 128 + ch * 32 + cb * 16 + l15;
                if (kg >= NK) { C[0][cb] = -3e38f; C[1][cb] = -3e38f; }
            }
        }

        // PV B-frag prologue: ct0 -> bt[0], ct1 -> bt[1]; in flight through softmax+barriers
        const unsigned short* mtp = MT + (size_t)(ch * 128 + l15) * NK + koff + tile * 128 + q4 * 8;
        s16x8 bt[2][4];
#pragma unroll
        for (int sk = 0; sk < 4; sk++) {
            bt[0][sk] = *(const s16x8*)(mtp + sk * 32);
            bt[1][sk] = *(const s16x8*)(mtp + (size_t)16 * NK + sk * 32);
        }

        // ================= softmax =================
        f32x4 mx[2];
#pragma unroll
        for (int st = 0; st < 2; st++)
#pragma unroll
            for (int v = 0; v < 4; v++) mx[st][v] = fmaxf(C[st][0][v], C[st][1][v]);
#pragma unroll
        for (int d = 1; d < 16; d <<= 1) {
#pragma unroll
            for (int st = 0; st < 2; st++)
#pragma unroll
                for (int v = 0; v < 4; v++) mx[st][v] = fmaxf(mx[st][v], __shfl_xor(mx[st][v], d, 16));
        }
        if (l15 == 0) {
            *(f32x4*)&smaxb[(ch * 2 + 0) * 16 + q4 * 4] = mx[0];
            *(f32x4*)&smaxb[(ch * 2 + 1) * 16 + q4 * 4] = mx[1];
        }
        lds_barrier();   // B1 (lgkm only -- K/bt prefetches stay in flight)
        f32x4 mnew[2]; mnew[0] = m_run[0]; mnew[1] = m_run[1];
#pragma unroll
        for (int cc = 0; cc < 4; cc++) {
#pragma unroll
            for (int st = 0; st < 2; st++) {
                f32x4 tv = *(const f32x4*)&smaxb[(cc * 2 + st) * 16 + q4 * 4];
#pragma unroll
                for (int v = 0; v < 4; v++) mnew[st][v] = fmaxf(mnew[st][v], tv[v]);
            }
        }
        f32x4 alpha[2];
#pragma unroll
        for (int st = 0; st < 2; st++)
#pragma unroll
            for (int v = 0; v < 4; v++) {
                alpha[st][v] = __expf(m_run[st][v] - mnew[st][v]);
                m_run[st][v] = mnew[st][v];
            }
        f32x4 ps[2]; ps[0] = 0.f; ps[1] = 0.f;
#pragma unroll
        for (int st = 0; st < 2; st++) {
#pragma unroll
            for (int cb = 0; cb < 2; cb++) {
#pragma unroll
                for (int v = 0; v < 4; v++) {
                    float p = __expf(C[st][cb][v] - mnew[st][v]);
                    ps[st][v] += p;
                    pbuf[(ch * 2 + st) * 512 + ((cb * 2 + kq) * 16 + q4 * 4 + v) * 8 + jj] = bf16_rn(p);
                }
            }
        }
#pragma unroll
        for (int d = 1; d < 16; d <<= 1) {
#pragma unroll
            for (int st = 0; st < 2; st++)
#pragma unroll
                for (int v = 0; v < 4; v++) ps[st][v] += __shfl_xor(ps[st][v], d, 16);
        }
        if (l15 == 0) {
            *(f32x4*)&ssumb[(ch * 2 + 0) * 16 + q4 * 4] = ps[0];
            *(f32x4*)&ssumb[(ch * 2 + 1) * 16 + q4 * 4] = ps[1];
        }
        lds_barrier();   // B2
        f32x4 ts[2]; ts[0] = 0.f; ts[1] = 0.f;
#pragma unroll
        for (int cc = 0; cc < 4; cc++) {
            ts[0] += *(const f32x4*)&ssumb[(cc * 2 + 0) * 16 + q4 * 4];
            ts[1] += *(const f32x4*)&ssumb[(cc * 2 + 1) * 16 + q4 * 4];
        }
#pragma unroll
        for (int st = 0; st < 2; st++)
#pragma unroll
            for (int v = 0; v < 4; v++) l_run[st][v] = l_run[st][v] * alpha[st][v] + ts[st][v];
#pragma unroll
        for (int st = 0; st < 2; st++)
#pragma unroll
            for (int ct = 0; ct < 8; ct++)
#pragma unroll
                for (int v = 0; v < 4; v++) O[st][ct][v] *= alpha[st][v];
        s16x8 pa[2][4];
#pragma unroll
        for (int st = 0; st < 2; st++)
#pragma unroll
            for (int sk = 0; sk < 4; sk++)
                pa[st][sk] = *(const s16x8*)&pbuf[((sk * 2 + st) * 512) + l * 8];

        // ================= PV phase: bt depth-2 pipeline =================
#pragma unroll
        for (int ct = 0; ct < 8; ct++) {
            s16x8 b0 = bt[ct & 1][0], b1 = bt[ct & 1][1], b2 = bt[ct & 1][2], b3 = bt[ct & 1][3];
            if (ct < 6) {
#pragma unroll
                for (int sk = 0; sk < 4; sk++)
                    bt[ct & 1][sk] = *(const s16x8*)(mtp + (size_t)(ct + 2) * 16 * NK + sk * 32);
            }
            O[0][ct] = __builtin_amdgcn_mfma_f32_16x16x32_bf16(pa[0][0], b0, O[0][ct], 0, 0, 0);
            O[1][ct] = __builtin_amdgcn_mfma_f32_16x16x32_bf16(pa[1][0], b0, O[1][ct], 0, 0, 0);
            O[0][ct] = __builtin_amdgcn_mfma_f32_16x16x32_bf16(pa[0][1], b1, O[0][ct], 0, 0, 0);
            O[1][ct] = __builtin_amdgcn_mfma_f32_16x16x32_bf16(pa[1][1], b1, O[1][ct], 0, 0, 0);
            O[0][ct] = __builtin_amdgcn_mfma_f32_16x16x32_bf16(pa[0][2], b2, O[0][ct], 0, 0, 0);
            O[1][ct] = __builtin_amdgcn_mfma_f32_16x16x32_bf16(pa[1][2], b2, O[1][ct], 0, 0, 0);
            O[0][ct] = __builtin_amdgcn_mfma_f32_16x16x32_bf16(pa[0][3], b3, O[0][ct], 0, 0, 0);
            O[1][ct] = __builtin_amdgcn_mfma_f32_16x16x32_bf16(pa[1][3], b3, O[1][ct], 0, 0, 0);
        }
        lds_barrier();   // protect pbuf reuse next tile (lgkm only)
    }

    // ================= epilogue =================
    if (nsplit == 2) {
        float* Od = Opart + (size_t)split * NQ * RD;
#pragma unroll
        for (int st = 0; st < 2; st++)
#pragma unroll
            for (int ct = 0; ct < 8; ct++)
#pragma unroll
                for (int v = 0; v < 4; v++)
                    Od[(size_t)(qbase + st * 16 + q4 * 4 + v) * RD + ch * 128 + ct * 16 + l15] =
                        O[st][ct][v];
        if (ch == 0 && l15 == 0) {
#pragma unroll
            for (int st = 0; st < 2; st++)
#pragma unroll
                for (int v = 0; v < 4; v++) {
                    mpart[split * NQ + qbase + st * 16 + q4 * 4 + v] = m_run[st][v];
                    lpart[split * NQ + qbase + st * 16 + q4 * 4 + v] = l_run[st][v];
                }
        }
    } else {
#pragma unroll
        for (int st = 0; st < 2; st++)
#pragma unroll
            for (int ct = 0; ct < 8; ct++)
#pragma unroll
                for (int v = 0; v < 4; v++)
                    out[(size_t)(qbase + st * 16 + q4 * 4 + v) * RD + ch * 128 + ct * 16 + l15] =
                        O[st][ct][v] / l_run[st][v];
    }
}

// ---------------- combine split-K partials ----------------
__global__ __launch_bounds__(256) void combine_kernel(const float* __restrict__ Opart,
                                                      const float* __restrict__ mpart,
                                                      const float* __restrict__ lpart,
                                                      float* __restrict__ out) {
    const int t = threadIdx.x;
    const int row = blockIdx.x * 2 + (t >> 7);
    const int d = (t & 127) * 4;
    float m0 = mpart[row], m1 = mpart[NQ + row];
    float l0 = lpart[row], l1 = lpart[NQ + row];
    float m = fmaxf(m0, m1);
    float w0 = __expf(m0 - m), w1 = __expf(m1 - m);
    float inv = 1.f / (w0 * l0 + w1 * l1);
    f32x4 o0 = *(const f32x4*)&Opart[(size_t)row * RD + d];
    f32x4 o1 = *(const f32x4*)&Opart[(size_t)NQ * RD + (size_t)row * RD + d];
    f32x4 r;
#pragma unroll
    for (int v = 0; v < 4; v++) r[v] = (o0[v] * w0 + o1[v] * w1) * inv;
    *(f32x4*)&out[(size_t)row * RD + d] = r;
}

// ---------------- fallback (ws too small): fp32, slow but exact ----------------
__global__ __launch_bounds__(256) void naive_kernel(const float* __restrict__ h,
                                                    const float* __restrict__ M,
                                                    float* __restrict__ out) {
    __shared__ float hs[16 * 520];
    __shared__ float ms[8 * 520];
    __shared__ float sdot[2][128];
    __shared__ float sm[16], sl[16], sal[16], sp[16][8];
    const int t = threadIdx.x;
    const int qbase = blockIdx.x * 16;
#pragma unroll
    for (int i = 0; i < 32; i++) {
        int e = t + i * 256;
        int row = e >> 9, col = e & 511;
        hs[row * 520 + col] = h[(size_t)(qbase + row) * RD + col];
    }
    if (t < 16) { sm[t] = -3e38f; sl[t] = 0.f; }
    float Oacc[32];
#pragma unroll
    for (int i = 0; i < 32; i++) Oacc[i] = 0.f;
    const int q = t >> 4;
    const int eb = (t & 15) * 32;

    for (int k0 = 0; k0 < NK; k0 += 8) {
        __syncthreads();
#pragma unroll
        for (int i = 0; i < 16; i++) {
            int e = t + i * 256;
            if (e < 4096) {
                int kk = e >> 9, col = e & 511;
                ms[kk * 520 + col] = M[(size_t)(k0 + kk) * RD + col];
            }
        }
        __syncthreads();
        {
            int pair = t & 127, half = t >> 7;
            int qq = pair & 15, kk = pair >> 4;
            const float* hp = &hs[qq * 520 + half * 256];
            const float* mp = &ms[kk * 520 + half * 256];
            float acc = 0.f;
#pragma unroll 8
            for (int e = 0; e < 256; e++) acc += hp[e] * mp[e];
            sdot[half][pair] = acc;
        }
        __syncthreads();
        if (t < 16) {
            int qq = t;
            float s8[8];
#pragma unroll
            for (int kk = 0; kk < 8; kk++) s8[kk] = sdot[0][qq + 16 * kk] + sdot[1][qq + 16 * kk];
            float mn = sm[qq];
#pragma unroll
            for (int kk = 0; kk < 8; kk++) mn = fmaxf(mn, s8[kk]);
            float al = __expf(sm[qq] - mn);
            float addl = 0.f;
#pragma unroll
            for (int kk = 0; kk < 8; kk++) { float p = __expf(s8[kk] - mn); sp[qq][kk] = p; addl += p; }
            sm[qq] = mn; sl[qq] = sl[qq] * al + addl; sal[qq] = al;
        }
        __syncthreads();
        {
            float al = sal[q];
#pragma unroll
            for (int i = 0; i < 32; i++) Oacc[i] *= al;
#pragma unroll
            for (int kk = 0; kk < 8; kk++) {
                float p = sp[q][kk];
                const float* mp = &ms[kk * 520 + eb];
#pragma unroll
                for (int i = 0; i < 32; i++) Oacc[i] += p * mp[i];
            }
        }
    }
    __syncthreads();
    float inv = 1.f / sl[q];
#pragma unroll
    for (int i = 0; i < 32; i++) out[(size_t)(qbase + q) * RD + eb + i] = Oacc[i] * inv;
}

extern "C" void kernel_launch(void* const* d_in, const int* in_sizes, int n_in,
                              void* d_out, int out_size, void* d_ws, size_t ws_size,
                              hipStream_t stream) {
    const float* h = (const float*)d_in[0];
    const float* M = (const float*)d_in[1];
    float* out = (float*)d_out;
    const size_t seg = (size_t)NK * RD;                      // u16 elems per converted buffer
    // Mhi + Mlo + MT + 8K u16 pad (tail reads stay in d_ws; 0xAA poison = finite bf16)
    const size_t base_bytes = (seg * 3ull + 8192ull) * 2ull;
    const size_t opart_bytes = 2ull * NQ * RD * 4ull;
    const size_t stat_bytes = 2ull * 2ull * NQ * 4ull;
    const size_t need_split = base_bytes + opart_bytes + stat_bytes;

    if (ws_size >= base_bytes) {
        unsigned short* Mhi = (unsigned short*)d_ws;
        unsigned short* Mlo = Mhi + seg;
        unsigned short* MT  = Mlo + seg;
        float* Opart = (float*)((char*)d_ws + base_bytes);
        float* mpart = Opart + 2ull * NQ * RD;
        float* lpart = mpart + 2ull * NQ;
        preconv_kernel<<<dim3(313, 8), 256, 0, stream>>>(M, Mhi, Mlo, MT);
        if (ws_size >= need_split) {
            flash6_kernel<<<512, 256, 0, stream>>>(h, Mhi, Mlo, MT, out, Opart, mpart, lpart, 2);
            combine_kernel<<<NQ / 2, 256, 0, stream>>>(Opart, mpart, lpart, out);
        } else {
            flash6_kernel<<<256, 256, 0, stream>>>(h, Mhi, Mlo, MT, out, Opart, mpart, lpart, 1);
        }
    } else {
        naive_kernel<<<512, 256, 0, stream>>>(h, M, out);
    }
}